// Round 8
// baseline (234.581 us; speedup 1.0000x reference)
//
#include <hip/hip_runtime.h>

#define EMBED 1024
#define NHEAD 16
#define HDIM  64
#define BB    2
#define SS    2048

typedef __bf16 bf16x8 __attribute__((ext_vector_type(8)));
typedef float  f32x4  __attribute__((ext_vector_type(4)));
typedef _Float16 f16x8 __attribute__((ext_vector_type(8)));
typedef __fp16 hf16x2 __attribute__((ext_vector_type(2)));

#if defined(__has_builtin)
#if __has_builtin(__builtin_amdgcn_exp2f)
#define EXP2(x) __builtin_amdgcn_exp2f(x)
#else
#define EXP2(x) exp2f(x)
#endif
#else
#define EXP2(x) exp2f(x)
#endif

__device__ __forceinline__ unsigned short f2bf(float f) {
  union { float f; unsigned u; } v; v.f = f;
  unsigned r = v.u + 0x7fffu + ((v.u >> 16) & 1u);
  return (unsigned short)(r >> 16);
}

__device__ __forceinline__ float bf2f(unsigned short u) {
  union { unsigned u; float f; } v; v.u = ((unsigned)u) << 16;
  return v.f;
}

__device__ __forceinline__ unsigned short f2h(float f) {
  union { _Float16 h; unsigned short u; } t;
  t.h = (_Float16)f;
  return t.u;
}

__device__ __forceinline__ void g2l16(const unsigned short* g, unsigned short* l) {
  __builtin_amdgcn_global_load_lds(
      (const __attribute__((address_space(1))) unsigned int*)g,
      (__attribute__((address_space(3))) unsigned int*)l, 16, 0, 0);
}

// ------- fused fp32->bf16 convert of x + 4 weights, + maskbias build -------
__global__ __launch_bounds__(256)
void cvt5_kernel(const float* __restrict__ x,  const float* __restrict__ Wq,
                 const float* __restrict__ Wk, const float* __restrict__ Wv,
                 const float* __restrict__ Wo, const int* __restrict__ mask,
                 unsigned short* __restrict__ xb,  unsigned short* __restrict__ Wqb,
                 unsigned short* __restrict__ Wkb, unsigned short* __restrict__ Wvb,
                 unsigned short* __restrict__ Wob, float* __restrict__ mbias) {
  const int i = blockIdx.x * 256 + threadIdx.x;
  if (i < (1 << 21)) {
    const float* src;
    unsigned short* dst;
    int j;
    if (i < (1 << 20)) {
      src = x; dst = xb; j = i;
    } else {
      const int t = i - (1 << 20);
      const int r = t >> 18;
      j = t & ((1 << 18) - 1);
      src = (r == 0) ? Wq : (r == 1) ? Wk : (r == 2) ? Wv : Wo;
      dst = (r == 0) ? Wqb : (r == 1) ? Wkb : (r == 2) ? Wvb : Wob;
    }
    const float4 f = ((const float4*)src)[j];
    ushort4 u;
    u.x = f2bf(f.x); u.y = f2bf(f.y); u.z = f2bf(f.z); u.w = f2bf(f.w);
    ((ushort4*)dst)[j] = u;
  } else {
    const int j = i - (1 << 21);  // 0..1023 int4 groups of mask
    const int4 m = ((const int4*)mask)[j];
    float4 o;
    o.x = m.x ? 0.f : -1e30f; o.y = m.y ? 0.f : -1e30f;
    o.z = m.z ? 0.f : -1e30f; o.w = m.w ? 0.f : -1e30f;
    ((float4*)mbias)[j] = o;
  }
}

// ------- shared GEMM core: C[m][n] = sum_k A[m][k]*Bm[n][k] -------
template <typename EpiFn>
__device__ __forceinline__
void gemm_core(const unsigned short* __restrict__ A,
               const unsigned short* __restrict__ Bm,
               int m0, int n0, EpiFn epi) {
  __shared__ unsigned short sA[128 * 64];
  __shared__ unsigned short sB[128 * 64];
  const int tid = threadIdx.x;
  const int l  = tid & 63;
  const int w  = tid >> 6;
  const int lm = l & 15;
  const int qd = l >> 4;
  const int wm = w & 1;
  const int wn = w >> 1;

  f32x4 acc[4][4];
#pragma unroll
  for (int i = 0; i < 4; ++i)
#pragma unroll
    for (int j = 0; j < 4; ++j) acc[i][j] = (f32x4){0.f, 0.f, 0.f, 0.f};

  for (int k0 = 0; k0 < EMBED; k0 += 64) {
#pragma unroll
    for (int i = 0; i < 4; ++i) {
      const int t = i * 256 + tid;
      const int r = t >> 3;
      const int c = (t & 7) ^ (r & 7);
      g2l16(A + (m0 + r) * EMBED + k0 + c * 8, &sA[(i * 256 + (w << 6)) * 8]);
      g2l16(Bm + (n0 + r) * EMBED + k0 + c * 8, &sB[(i * 256 + (w << 6)) * 8]);
    }
    __syncthreads();
#pragma unroll
    for (int kk = 0; kk < 2; ++kk) {
      bf16x8 af[4], bfr[4];
#pragma unroll
      for (int mi = 0; mi < 4; ++mi) {
        const int R = wm * 64 + mi * 16 + lm;
        const int ch = R * 8 + (((kk << 2) + qd) ^ (R & 7));
        af[mi] = *(const bf16x8*)&sA[ch * 8];
      }
#pragma unroll
      for (int ni = 0; ni < 4; ++ni) {
        const int R = wn * 64 + ni * 16 + lm;
        const int ch = R * 8 + (((kk << 2) + qd) ^ (R & 7));
        bfr[ni] = *(const bf16x8*)&sB[ch * 8];
      }
#pragma unroll
      for (int mi = 0; mi < 4; ++mi)
#pragma unroll
        for (int ni = 0; ni < 4; ++ni)
          acc[mi][ni] = __builtin_amdgcn_mfma_f32_16x16x32_bf16(
              af[mi], bfr[ni], acc[mi][ni], 0, 0, 0);
    }
    __syncthreads();
  }

#pragma unroll
  for (int mi = 0; mi < 4; ++mi)
#pragma unroll
    for (int ni = 0; ni < 4; ++ni) {
      const int mb = m0 + wm * 64 + mi * 16 + qd * 4;  // rows mb..mb+3
      const int n  = n0 + wn * 64 + ni * 16 + lm;
      epi(acc[mi][ni], mb, n);
    }
}

// supertile decode for L2 locality: 16 consecutive blocks = 2a x 8b tile grp
__device__ __forceinline__ void decode_tile(int flat, int& a0, int& b0) {
  const int sub = flat & 15;
  const int g = flat >> 4;           // 0..15
  a0 = ((g >> 2) * 2 + (sub >> 3));  // 0..7  (feature dim / 128)
  b0 = ((g & 3) * 8 + (sub & 7));    // 0..31 (token dim / 128)
}

// ------- fused Q/K/V projection -------
// z=0: Q = Wq·x^T ->(b,h,s,d) bf16, pre-scaled by (1/8)*log2(e)
// z=1: K = Wk·x^T ->(b,h,s,d) bf16, tokens PERMUTED within 32-groups so the
//      attn S^T lane layout becomes PV-contiguous: token w sits at row
//      ((w>>2)&1)*16 + ((w>>3)&3)*4 + (w&3) of its 32-block.
// z=2: V = x·Wv^T ->(b,h,d,s) fp16 (transposed, for PV MFMA)
__global__ __launch_bounds__(256)
void gemm_qkv(const unsigned short* __restrict__ xb,
              const unsigned short* __restrict__ Wqb,
              const unsigned short* __restrict__ Wkb,
              const unsigned short* __restrict__ Wvb,
              const float* __restrict__ bq, const float* __restrict__ bk,
              const float* __restrict__ bv,
              unsigned short* __restrict__ Qb, unsigned short* __restrict__ Kb,
              unsigned short* __restrict__ VTb) {
  const int z = blockIdx.y;
  int a0, b0;
  decode_tile(blockIdx.x, a0, b0);
  if (z < 2) {
    const unsigned short* A = z ? Wkb : Wqb;
    const float* bias = z ? bk : bq;
    unsigned short* O = z ? Kb : Qb;
    const float scale = z ? 1.0f : 0.125f * 1.4426950408889634f;
    gemm_core(A, xb, a0 * 128, b0 * 128, [&](const f32x4& v, int mb, int n) {
      const float4 bvv = *(const float4*)&bias[mb];
      const int h = mb >> 6, d0 = mb & 63;
      const int b = n >> 11, s = n & 2047;
      int sw = s;
      if (z == 1)
        sw = (s & ~31) | (((s >> 2) & 1) << 4) | (((s >> 3) & 3) << 2) | (s & 3);
      ushort4 u;
      u.x = f2bf((v.x + bvv.x) * scale); u.y = f2bf((v.y + bvv.y) * scale);
      u.z = f2bf((v.z + bvv.z) * scale); u.w = f2bf((v.w + bvv.w) * scale);
      *(ushort4*)&O[(((b * NHEAD + h) * SS) + sw) * HDIM + d0] = u;
    });
  } else {
    gemm_core(xb, Wvb, b0 * 128, a0 * 128, [&](const f32x4& v, int mb, int n) {
      const float bvv = bv[n];
      const int b = mb >> 11, s = mb & 2047;
      const int h = n >> 6, d = n & 63;
      ushort4 u;
      u.x = f2h(v.x + bvv); u.y = f2h(v.y + bvv);
      u.z = f2h(v.z + bvv); u.w = f2h(v.w + bvv);
      *(ushort4*)&VTb[(((b * NHEAD + h) * HDIM) + d) * SS + s] = u;
    });
  }
}

// ------- output projection: fp32 out -------
__global__ __launch_bounds__(256)
void gemm_out(const unsigned short* __restrict__ Wob,
              const unsigned short* __restrict__ Ob,
              const float* __restrict__ bo, float* __restrict__ out) {
  int a0, b0;
  decode_tile(blockIdx.x, a0, b0);
  gemm_core(Wob, Ob, a0 * 128, b0 * 128, [&](const f32x4& v, int mb, int n) {
    const float4 bvv = *(const float4*)&bo[mb];
    float4 o;
    o.x = v.x + bvv.x; o.y = v.y + bvv.y; o.z = v.z + bvv.z; o.w = v.w + bvv.w;
    *(float4*)&out[n * EMBED + mb] = o;
  });
}

// ------- flash attention: key-split x2, 4 waves = (q-half x d-half) --------
// grid (32 qtiles of 64q, 16 heads, b*2+split), 256 threads.
// Round-6 lesson: 16q/wave -> LDS pipe ~90% busy (each wave re-reads K/V for
// only 16q). Round-7 lesson: 32q/wave with full-d PV needs 72 VGPR > 64 ->
// waves/SIMD halve -> latency-bound. This round: wave (qh,dh) computes 32
// queries (qh half) but only 32 output dims (dh half). QK^T is DUPLICATED
// across the 2 dh-waves (MFMA pipe has headroom) while Od halves to 16 regs:
// target VGPR ~56 <= 64 keeps 8 waves/SIMD AND LDS reads drop to 48/64 of
// round 6 (K: 8 reads serve 32q; V: 4 reads for 32 dims).
__global__ __launch_bounds__(256)
void attn_kernel(const unsigned short* __restrict__ Q,
                 const unsigned short* __restrict__ K,
                 const unsigned short* __restrict__ VT,
                 const float* __restrict__ mbias,
                 unsigned short* __restrict__ Opart,
                 float* __restrict__ Lpart) {
  __shared__ unsigned short sK[64 * 64];  // bf16, row=key, chunk-swizzled
  __shared__ unsigned short sV[64 * 64];  // fp16, row=dim, chunk-swizzled
  __shared__ float sMB[SS / 2];           // mask bias for this split (4KB)
  const int tid = threadIdx.x;
  const int l = tid & 63, w = tid >> 6;   // 4 waves
  const int lm = l & 15, qd = l >> 4;
  const int qh = w & 1, dh = w >> 1;      // wave role: (q-half, d-half)
  const int b = blockIdx.z & 1, sp = blockIdx.z >> 1, h = blockIdx.y;
  const int q0 = blockIdx.x * 64 + qh * 32;  // wave: q0 .. q0+31
  const unsigned short* Qh = Q + ((b * NHEAD + h) * SS) * HDIM;
  const unsigned short* Kh = K + ((b * NHEAD + h) * SS) * HDIM;
  const unsigned short* Vh = VT + ((b * NHEAD + h) * HDIM) * SS;
  const float* mb = mbias + b * SS + sp * (SS / 2);
  unsigned short* Op = Opart + sp * (BB * SS * EMBED);
  float* Lp = Lpart + sp * (BB * NHEAD * SS);
  const int kb0 = sp * (SS / 2);

  bf16x8 qf[2][2];
#pragma unroll
  for (int g = 0; g < 2; ++g) {
    qf[g][0] = *(const bf16x8*)&Qh[(q0 + g * 16 + lm) * HDIM + qd * 8];
    qf[g][1] = *(const bf16x8*)&Qh[(q0 + g * 16 + lm) * HDIM + 32 + qd * 8];
  }

  auto stageKV = [&](int kb) {
#pragma unroll
    for (int i = 0; i < 2; ++i) {
      const int t = i * 256 + tid;
      const int r = t >> 3;
      const int c = (t & 7) ^ (r & 7);
      g2l16(Kh + (kb + r) * HDIM + c * 8, &sK[(i * 256 + (w << 6)) * 8]);
      g2l16(Vh + r * SS + kb + c * 8, &sV[(i * 256 + (w << 6)) * 8]);
    }
  };

  // one-time mask-bias stage (4KB: 256 lanes x 16B)
  g2l16((const unsigned short*)(mb + tid * 4), (unsigned short*)&sMB[w * 256]);

  f32x4 Od[2][2];  // [g][dtl] - only this wave's d-half
#pragma unroll
  for (int g = 0; g < 2; ++g)
#pragma unroll
    for (int i = 0; i < 2; ++i) Od[g][i] = (f32x4){0.f, 0.f, 0.f, 0.f};
  float lsum[2] = {0.f, 0.f};

  const int NT = (SS / 2) / 64;
  for (int t = 0; t < NT; ++t) {
    // Overwrite of sK/sV safe: trailing barrier of iter t-1. The leading
    // __syncthreads' implicit vmcnt(0) drain publishes this tile.
    stageKV(kb0 + t * 64);
    __syncthreads();

    // Per 32-key group p: QK^T (j=2p,2p+1) -> exp -> pack, then PV on this
    // wave's d-half only. K-frags read ONCE, used by BOTH q-groups.
#pragma unroll
    for (int p = 0; p < 2; ++p) {
      union PK { hf16x2 h2[4]; f16x8 v; } pk0, pk1;
#pragma unroll
      for (int jj = 0; jj < 2; ++jj) {
        const int j = p * 2 + jj;
        const int R = j * 16 + lm;
        const bf16x8 k0 = *(const bf16x8*)&sK[(R * 8 + (qd ^ (lm & 7))) * 8];
        const bf16x8 k1 = *(const bf16x8*)&sK[(R * 8 + ((4 + qd) ^ (lm & 7))) * 8];
        const float4 bj = *(const float4*)&sMB[t * 64 + p * 32 + qd * 8 + jj * 4];
        const f32x4 binit = (f32x4){bj.x, bj.y, bj.z, bj.w};
#pragma unroll
        for (int g = 0; g < 2; ++g) {
          f32x4 t0 = binit;
          __builtin_amdgcn_s_setprio(1);
          t0 = __builtin_amdgcn_mfma_f32_16x16x32_bf16(k0, qf[g][0], t0, 0, 0, 0);
          t0 = __builtin_amdgcn_mfma_f32_16x16x32_bf16(k1, qf[g][1], t0, 0, 0, 0);
          __builtin_amdgcn_s_setprio(0);
          const float p0 = EXP2(t0[0]);
          const float p1 = EXP2(t0[1]);
          const float p2 = EXP2(t0[2]);
          const float p3 = EXP2(t0[3]);
          lsum[g] += (p0 + p1) + (p2 + p3);
          const hf16x2 lo = __builtin_amdgcn_cvt_pkrtz(p0, p1);
          const hf16x2 hi = __builtin_amdgcn_cvt_pkrtz(p2, p3);
          if (g == 0) { pk0.h2[jj * 2] = lo; pk0.h2[jj * 2 + 1] = hi; }
          else        { pk1.h2[jj * 2] = lo; pk1.h2[jj * 2 + 1] = hi; }
        }
      }
      const f16x8 pf0 = pk0.v;
      const f16x8 pf1 = pk1.v;
      // O^T += V-frag x P-frag on dims [dh*32, dh*32+32) only.
      __builtin_amdgcn_s_setprio(1);
#pragma unroll
      for (int dtl = 0; dtl < 2; ++dtl) {
        const int dt = dh * 2 + dtl;
        const f16x8 vf =
            *(const f16x8*)&sV[(dt * 16 + lm) * 64 + ((p * 4 + qd) ^ (lm & 7)) * 8];
        Od[0][dtl] = __builtin_amdgcn_mfma_f32_16x16x32_f16(vf, pf0, Od[0][dtl], 0, 0, 0);
        Od[1][dtl] = __builtin_amdgcn_mfma_f32_16x16x32_f16(vf, pf1, Od[1][dtl], 0, 0, 0);
      }
      __builtin_amdgcn_s_setprio(0);
    }
    __syncthreads();  // all waves done reading sK/sV before next stage
  }

#pragma unroll
  for (int g = 0; g < 2; ++g) {
    float ls = lsum[g];
    ls += __shfl_xor(ls, 16);
    ls += __shfl_xor(ls, 32);
    if (qd == 0 && dh == 0) Lp[(b * NHEAD + h) * SS + q0 + g * 16 + lm] = ls;
    // O^T C-layout: lane (qd,lm) holds q=lm(+g*16), dims dt*16 + qd*4 + r
#pragma unroll
    for (int dtl = 0; dtl < 2; ++dtl) {
      const int dt = dh * 2 + dtl;
      ushort4 u;
      u.x = f2bf(Od[g][dtl][0]); u.y = f2bf(Od[g][dtl][1]);
      u.z = f2bf(Od[g][dtl][2]); u.w = f2bf(Od[g][dtl][3]);
      *(ushort4*)&Op[(b * SS + q0 + g * 16 + lm) * EMBED + h * HDIM +
                     dt * 16 + qd * 4] = u;
    }
  }
}

// ------- combine: Ob = (P0 + P1) / (l0 + l1), bf16 out -------
__global__ __launch_bounds__(256)
void combine_kernel(const unsigned short* __restrict__ Opart,
                    const float* __restrict__ Lpart,
                    unsigned short* __restrict__ Ob) {
  const int i = blockIdx.x * 256 + threadIdx.x;  // per 8 elems
  const int base = i * 8;
  const int token = base >> 10;       // 0..4095
  const int h = (base >> 6) & 15;
  const int b = token >> 11, q = token & 2047;
  const int lidx = (b * NHEAD + h) * SS + q;
  const float ls = Lpart[lidx] + Lpart[BB * NHEAD * SS + lidx];
  const float rinv = 1.f / ls;
  const ushort4* p0 = (const ushort4*)&Opart[base];
  const ushort4* p1 = (const ushort4*)&Opart[BB * SS * EMBED + base];
  ushort4 o[2];
#pragma unroll
  for (int k = 0; k < 2; ++k) {
    const ushort4 a = p0[k], c = p1[k];
    o[k].x = f2bf((bf2f(a.x) + bf2f(c.x)) * rinv);
    o[k].y = f2bf((bf2f(a.y) + bf2f(c.y)) * rinv);
    o[k].z = f2bf((bf2f(a.z) + bf2f(c.z)) * rinv);
    o[k].w = f2bf((bf2f(a.w) + bf2f(c.w)) * rinv);
  }
  *(ushort4*)&Ob[base] = o[0];
  *(ushort4*)&Ob[base + 4] = o[1];
}

extern "C" void kernel_launch(void* const* d_in, const int* in_sizes, int n_in,
                              void* d_out, int out_size, void* d_ws, size_t ws_size,
                              hipStream_t stream) {
  const float* x  = (const float*)d_in[0];
  const int* mask = (const int*)d_in[1];
  const float* Wq = (const float*)d_in[2];
  const float* bq = (const float*)d_in[3];
  const float* Wk = (const float*)d_in[4];
  const float* bk = (const float*)d_in[5];
  const float* Wv = (const float*)d_in[6];
  const float* bv = (const float*)d_in[7];
  const float* Wo = (const float*)d_in[8];
  const float* bo = (const float*)d_in[9];
  float* out = (float*)d_out;

  char* ws = (char*)d_ws;
  const size_t MB = 1024 * 1024;
  // xb [0,8MB) dead after gemm_qkv -> Ob reuses it (combine writes, gemm_out reads)
  unsigned short* xb  = (unsigned short*)(ws);
  unsigned short* Ob  = (unsigned short*)(ws);
  unsigned short* Wqb = (unsigned short*)(ws + 8 * MB);   // 2MB each
  unsigned short* Wkb = Wqb + 1024 * 1024;
  unsigned short* Wvb = Wkb + 1024 * 1024;
  unsigned short* Wob = Wvb + 1024 * 1024;                 // alive till gemm_out
  unsigned short* Qb  = (unsigned short*)(ws + 16 * MB);  // 8MB
  unsigned short* Kb  = (unsigned short*)(ws + 24 * MB);  // 8MB
  unsigned short* VTb = (unsigned short*)(ws + 32 * MB);  // 8MB (fp16)
  unsigned short* Opart = (unsigned short*)(ws + 40 * MB); // 2 x 8MB bf16
  float* mbb   = (float*)(ws + 56 * MB);                   // 16KB
  float* Lpart = (float*)(ws + 56 * MB + 64 * 1024);       // 2 x 256KB

  cvt5_kernel<<<8196, 256, 0, stream>>>(x, Wq, Wk, Wv, Wo, mask,
                                        xb, Wqb, Wkb, Wvb, Wob, mbb);
  gemm_qkv<<<dim3(256, 3), 256, 0, stream>>>(xb, Wqb, Wkb, Wvb, bq, bk, bv,
                                             Qb, Kb, VTb);
  attn_kernel<<<dim3(32, 16, 4), 256, 0, stream>>>(Qb, Kb, VTb, mbb,
                                                   Opart, Lpart);
  combine_kernel<<<2048, 256, 0, stream>>>(Opart, Lpart, Ob);
  gemm_out<<<256, 256, 0, stream>>>(Wob, Ob, bo, out);
}

// Round 9
// 226.970 us; speedup vs baseline: 1.0335x; 1.0335x over previous
//
#include <hip/hip_runtime.h>

#define EMBED 1024
#define NHEAD 16
#define HDIM  64
#define BB    2
#define SS    2048

typedef __bf16 bf16x8 __attribute__((ext_vector_type(8)));
typedef float  f32x4  __attribute__((ext_vector_type(4)));
typedef _Float16 f16x8 __attribute__((ext_vector_type(8)));
typedef __fp16 hf16x2 __attribute__((ext_vector_type(2)));
typedef unsigned short u16x8 __attribute__((ext_vector_type(8)));

#if defined(__has_builtin)
#if __has_builtin(__builtin_amdgcn_exp2f)
#define EXP2(x) __builtin_amdgcn_exp2f(x)
#else
#define EXP2(x) exp2f(x)
#endif
#else
#define EXP2(x) exp2f(x)
#endif

__device__ __forceinline__ unsigned short f2bf(float f) {
  union { float f; unsigned u; } v; v.f = f;
  unsigned r = v.u + 0x7fffu + ((v.u >> 16) & 1u);
  return (unsigned short)(r >> 16);
}

__device__ __forceinline__ float bf2f(unsigned short u) {
  union { unsigned u; float f; } v; v.u = ((unsigned)u) << 16;
  return v.f;
}

__device__ __forceinline__ unsigned short f2h(float f) {
  union { _Float16 h; unsigned short u; } t;
  t.h = (_Float16)f;
  return t.u;
}

__device__ __forceinline__ void g2l16(const unsigned short* g, unsigned short* l) {
  __builtin_amdgcn_global_load_lds(
      (const __attribute__((address_space(1))) unsigned int*)g,
      (__attribute__((address_space(3))) unsigned int*)l, 16, 0, 0);
}

// ------- fused fp32->bf16 convert of x + 4 weights, + maskbias build -------
__global__ __launch_bounds__(256)
void cvt5_kernel(const float* __restrict__ x,  const float* __restrict__ Wq,
                 const float* __restrict__ Wk, const float* __restrict__ Wv,
                 const float* __restrict__ Wo, const int* __restrict__ mask,
                 unsigned short* __restrict__ xb,  unsigned short* __restrict__ Wqb,
                 unsigned short* __restrict__ Wkb, unsigned short* __restrict__ Wvb,
                 unsigned short* __restrict__ Wob, float* __restrict__ mbias) {
  const int i = blockIdx.x * 256 + threadIdx.x;
  if (i < (1 << 21)) {
    const float* src;
    unsigned short* dst;
    int j;
    if (i < (1 << 20)) {
      src = x; dst = xb; j = i;
    } else {
      const int t = i - (1 << 20);
      const int r = t >> 18;
      j = t & ((1 << 18) - 1);
      src = (r == 0) ? Wq : (r == 1) ? Wk : (r == 2) ? Wv : Wo;
      dst = (r == 0) ? Wqb : (r == 1) ? Wkb : (r == 2) ? Wvb : Wob;
    }
    const float4 f = ((const float4*)src)[j];
    ushort4 u;
    u.x = f2bf(f.x); u.y = f2bf(f.y); u.z = f2bf(f.z); u.w = f2bf(f.w);
    ((ushort4*)dst)[j] = u;
  } else {
    const int j = i - (1 << 21);  // 0..1023 int4 groups of mask
    const int4 m = ((const int4*)mask)[j];
    float4 o;
    o.x = m.x ? 0.f : -1e30f; o.y = m.y ? 0.f : -1e30f;
    o.z = m.z ? 0.f : -1e30f; o.w = m.w ? 0.f : -1e30f;
    ((float4*)mbias)[j] = o;
  }
}

// ------- shared GEMM core: C[m][n] = sum_k A[m][k]*Bm[n][k] -------
template <typename EpiFn>
__device__ __forceinline__
void gemm_core(const unsigned short* __restrict__ A,
               const unsigned short* __restrict__ Bm,
               int m0, int n0, EpiFn epi) {
  __shared__ unsigned short sA[128 * 64];
  __shared__ unsigned short sB[128 * 64];
  const int tid = threadIdx.x;
  const int l  = tid & 63;
  const int w  = tid >> 6;
  const int lm = l & 15;
  const int qd = l >> 4;
  const int wm = w & 1;
  const int wn = w >> 1;

  f32x4 acc[4][4];
#pragma unroll
  for (int i = 0; i < 4; ++i)
#pragma unroll
    for (int j = 0; j < 4; ++j) acc[i][j] = (f32x4){0.f, 0.f, 0.f, 0.f};

  for (int k0 = 0; k0 < EMBED; k0 += 64) {
#pragma unroll
    for (int i = 0; i < 4; ++i) {
      const int t = i * 256 + tid;
      const int r = t >> 3;
      const int c = (t & 7) ^ (r & 7);
      g2l16(A + (m0 + r) * EMBED + k0 + c * 8, &sA[(i * 256 + (w << 6)) * 8]);
      g2l16(Bm + (n0 + r) * EMBED + k0 + c * 8, &sB[(i * 256 + (w << 6)) * 8]);
    }
    __syncthreads();
#pragma unroll
    for (int kk = 0; kk < 2; ++kk) {
      bf16x8 af[4], bfr[4];
#pragma unroll
      for (int mi = 0; mi < 4; ++mi) {
        const int R = wm * 64 + mi * 16 + lm;
        const int ch = R * 8 + (((kk << 2) + qd) ^ (R & 7));
        af[mi] = *(const bf16x8*)&sA[ch * 8];
      }
#pragma unroll
      for (int ni = 0; ni < 4; ++ni) {
        const int R = wn * 64 + ni * 16 + lm;
        const int ch = R * 8 + (((kk << 2) + qd) ^ (R & 7));
        bfr[ni] = *(const bf16x8*)&sB[ch * 8];
      }
#pragma unroll
      for (int mi = 0; mi < 4; ++mi)
#pragma unroll
        for (int ni = 0; ni < 4; ++ni)
          acc[mi][ni] = __builtin_amdgcn_mfma_f32_16x16x32_bf16(
              af[mi], bfr[ni], acc[mi][ni], 0, 0, 0);
    }
    __syncthreads();
  }

#pragma unroll
  for (int mi = 0; mi < 4; ++mi)
#pragma unroll
    for (int ni = 0; ni < 4; ++ni) {
      const int mb = m0 + wm * 64 + mi * 16 + qd * 4;  // rows mb..mb+3
      const int n  = n0 + wn * 64 + ni * 16 + lm;
      epi(acc[mi][ni], mb, n);
    }
}

// supertile decode for L2 locality: 16 consecutive blocks = 2a x 8b tile grp
__device__ __forceinline__ void decode_tile(int flat, int& a0, int& b0) {
  const int sub = flat & 15;
  const int g = flat >> 4;           // 0..15
  a0 = ((g >> 2) * 2 + (sub >> 3));  // 0..7  (feature dim / 128)
  b0 = ((g & 3) * 8 + (sub & 7));    // 0..31 (token dim / 128)
}

// ------- fused Q/K/V projection -------
// z=0: Q = Wq·x^T ->(b,h,s,d) bf16, pre-scaled by (1/8)*log2(e)
// z=1: K = Wk·x^T ->(b,h,s,d) bf16, tokens PERMUTED within 32-groups so the
//      attn S^T lane layout becomes PV-contiguous: token w sits at row
//      ((w>>2)&1)*16 + ((w>>3)&3)*4 + (w&3) of its 32-block.
// z=2: V = x·Wv^T ->(b,h,d,s) fp16 (transposed, for PV MFMA)
__global__ __launch_bounds__(256)
void gemm_qkv(const unsigned short* __restrict__ xb,
              const unsigned short* __restrict__ Wqb,
              const unsigned short* __restrict__ Wkb,
              const unsigned short* __restrict__ Wvb,
              const float* __restrict__ bq, const float* __restrict__ bk,
              const float* __restrict__ bv,
              unsigned short* __restrict__ Qb, unsigned short* __restrict__ Kb,
              unsigned short* __restrict__ VTb) {
  const int z = blockIdx.y;
  int a0, b0;
  decode_tile(blockIdx.x, a0, b0);
  if (z < 2) {
    const unsigned short* A = z ? Wkb : Wqb;
    const float* bias = z ? bk : bq;
    unsigned short* O = z ? Kb : Qb;
    const float scale = z ? 1.0f : 0.125f * 1.4426950408889634f;
    gemm_core(A, xb, a0 * 128, b0 * 128, [&](const f32x4& v, int mb, int n) {
      const float4 bvv = *(const float4*)&bias[mb];
      const int h = mb >> 6, d0 = mb & 63;
      const int b = n >> 11, s = n & 2047;
      int sw = s;
      if (z == 1)
        sw = (s & ~31) | (((s >> 2) & 1) << 4) | (((s >> 3) & 3) << 2) | (s & 3);
      ushort4 u;
      u.x = f2bf((v.x + bvv.x) * scale); u.y = f2bf((v.y + bvv.y) * scale);
      u.z = f2bf((v.z + bvv.z) * scale); u.w = f2bf((v.w + bvv.w) * scale);
      *(ushort4*)&O[(((b * NHEAD + h) * SS) + sw) * HDIM + d0] = u;
    });
  } else {
    gemm_core(xb, Wvb, b0 * 128, a0 * 128, [&](const f32x4& v, int mb, int n) {
      const float bvv = bv[n];
      const int b = mb >> 11, s = mb & 2047;
      const int h = n >> 6, d = n & 63;
      ushort4 u;
      u.x = f2h(v.x + bvv); u.y = f2h(v.y + bvv);
      u.z = f2h(v.z + bvv); u.w = f2h(v.w + bvv);
      *(ushort4*)&VTb[(((b * NHEAD + h) * HDIM) + d) * SS + s] = u;
    });
  }
}

// ------- output projection fused with split-combine: fp32 out -------------
// B-matrix = (Opart0 + Opart1) * rinv, combined in registers during staging.
// BK=64 aligns with head boundaries -> h = k0>>6 is fixed per k-step, so the
// softmax normalizer rinv is one scalar per B-row per k-step. A stays on the
// global_load_lds fast path; B goes global->reg->combine->ds_write into the
// SAME swizzled slot layout gemm_core's fragment reads expect.
__global__ __launch_bounds__(256)
void gemm_out(const unsigned short* __restrict__ Wob,
              const unsigned short* __restrict__ Opart,
              const float* __restrict__ Lpart,
              const float* __restrict__ bo, float* __restrict__ out) {
  __shared__ unsigned short sA[128 * 64];
  __shared__ unsigned short sB[128 * 64];
  int a0, b0;
  decode_tile(blockIdx.x, a0, b0);
  const int m0 = a0 * 128, n0 = b0 * 128;
  const int tid = threadIdx.x;
  const int l  = tid & 63;
  const int w  = tid >> 6;
  const int lm = l & 15;
  const int qd = l >> 4;
  const int wm = w & 1;
  const int wn = w >> 1;

  f32x4 acc[4][4];
#pragma unroll
  for (int i = 0; i < 4; ++i)
#pragma unroll
    for (int j = 0; j < 4; ++j) acc[i][j] = (f32x4){0.f, 0.f, 0.f, 0.f};

  for (int k0 = 0; k0 < EMBED; k0 += 64) {
    const int h = k0 >> 6;  // head of this k-slice
#pragma unroll
    for (int i = 0; i < 4; ++i) {
      const int t = i * 256 + tid;
      const int r = t >> 3;
      const int c = (t & 7) ^ (r & 7);
      g2l16(Wob + (m0 + r) * EMBED + k0 + c * 8, &sA[(i * 256 + (w << 6)) * 8]);
    }
#pragma unroll
    for (int i = 0; i < 4; ++i) {
      const int t = i * 256 + tid;
      const int r = t >> 3;
      const int c = (t & 7) ^ (r & 7);
      const int n = n0 + r;                      // token 0..4095
      const int bb = n >> 11, q = n & 2047;
      const int lidx = (bb * NHEAD + h) * SS + q;
      const float rinv = 1.f / (Lpart[lidx] + Lpart[BB * NHEAD * SS + lidx]);
      const u16x8 pa = *(const u16x8*)&Opart[n * EMBED + k0 + c * 8];
      const u16x8 pb =
          *(const u16x8*)&Opart[BB * SS * EMBED + n * EMBED + k0 + c * 8];
      u16x8 o;
#pragma unroll
      for (int e = 0; e < 8; ++e)
        o[e] = f2bf((bf2f(pa[e]) + bf2f(pb[e])) * rinv);
      *(u16x8*)&sB[(i * 256 + tid) * 8] = o;
    }
    __syncthreads();
#pragma unroll
    for (int kk = 0; kk < 2; ++kk) {
      bf16x8 af[4], bfr[4];
#pragma unroll
      for (int mi = 0; mi < 4; ++mi) {
        const int R = wm * 64 + mi * 16 + lm;
        const int ch = R * 8 + (((kk << 2) + qd) ^ (R & 7));
        af[mi] = *(const bf16x8*)&sA[ch * 8];
      }
#pragma unroll
      for (int ni = 0; ni < 4; ++ni) {
        const int R = wn * 64 + ni * 16 + lm;
        const int ch = R * 8 + (((kk << 2) + qd) ^ (R & 7));
        bfr[ni] = *(const bf16x8*)&sB[ch * 8];
      }
#pragma unroll
      for (int mi = 0; mi < 4; ++mi)
#pragma unroll
        for (int ni = 0; ni < 4; ++ni)
          acc[mi][ni] = __builtin_amdgcn_mfma_f32_16x16x32_bf16(
              af[mi], bfr[ni], acc[mi][ni], 0, 0, 0);
    }
    __syncthreads();
  }

#pragma unroll
  for (int mi = 0; mi < 4; ++mi)
#pragma unroll
    for (int ni = 0; ni < 4; ++ni) {
      const int mb = m0 + wm * 64 + mi * 16 + qd * 4;
      const int n  = n0 + wn * 64 + ni * 16 + lm;
      const float4 bvv = *(const float4*)&bo[mb];
      float4 o;
      o.x = acc[mi][ni][0] + bvv.x; o.y = acc[mi][ni][1] + bvv.y;
      o.z = acc[mi][ni][2] + bvv.z; o.w = acc[mi][ni][3] + bvv.w;
      *(float4*)&out[n * EMBED + mb] = o;
    }
}

// ------- flash attention, key-split x2, 16 q per wave, 8 blocks/CU ---------
// (round-6 verified version: 51.4us, VGPR 40, zero conflicts)
// grid (32 qtiles, 16 heads, b*2+split). Each block: 4 waves x 16 q,
// 16 64-key tiles, single-buffered K/V (20480B LDS = 8 blocks/CU capacity).
__global__ __launch_bounds__(256, 6)
void attn_kernel(const unsigned short* __restrict__ Q,
                 const unsigned short* __restrict__ K,
                 const unsigned short* __restrict__ VT,
                 const float* __restrict__ mbias,
                 unsigned short* __restrict__ Opart,
                 float* __restrict__ Lpart) {
  __shared__ unsigned short sK[64 * 64];  // bf16, row=key, chunk-swizzled
  __shared__ unsigned short sV[64 * 64];  // fp16, row=dim, chunk-swizzled
  __shared__ float sMB[SS / 2];           // mask bias for this split (4KB)
  const int tid = threadIdx.x;
  const int l = tid & 63, w = tid >> 6;
  const int lm = l & 15, qd = l >> 4;
  const int b = blockIdx.z & 1, sp = blockIdx.z >> 1, h = blockIdx.y;
  const int q0 = blockIdx.x * 64 + w * 16;  // wave: q0 .. q0+15
  const unsigned short* Qh = Q + ((b * NHEAD + h) * SS) * HDIM;
  const unsigned short* Kh = K + ((b * NHEAD + h) * SS) * HDIM;
  const unsigned short* Vh = VT + ((b * NHEAD + h) * HDIM) * SS;
  const float* mb = mbias + b * SS + sp * (SS / 2);
  unsigned short* Op = Opart + sp * (BB * SS * EMBED);
  float* Lp = Lpart + sp * (BB * NHEAD * SS);
  const int kb0 = sp * (SS / 2);

  bf16x8 qf[2];
  qf[0] = *(const bf16x8*)&Qh[(q0 + lm) * HDIM + qd * 8];
  qf[1] = *(const bf16x8*)&Qh[(q0 + lm) * HDIM + 32 + qd * 8];

  auto stageKV = [&](int kb) {
#pragma unroll
    for (int i = 0; i < 2; ++i) {
      const int t = i * 256 + tid;
      const int r = t >> 3;
      const int c = (t & 7) ^ (r & 7);
      g2l16(Kh + (kb + r) * HDIM + c * 8, &sK[(i * 256 + (w << 6)) * 8]);
      g2l16(Vh + r * SS + kb + c * 8, &sV[(i * 256 + (w << 6)) * 8]);
    }
  };

  // one-time mask-bias stage (4KB: 256 lanes x 16B)
  g2l16((const unsigned short*)(mb + tid * 4), (unsigned short*)&sMB[w * 256]);

  f32x4 Od[4];
#pragma unroll
  for (int i = 0; i < 4; ++i) Od[i] = (f32x4){0.f, 0.f, 0.f, 0.f};
  float lsum = 0.f;

  const int NT = (SS / 2) / 64;
  for (int t = 0; t < NT; ++t) {
    // Overwrite of sK/sV is safe: trailing barrier of iter t-1 guarantees
    // all waves finished reading. Leading __syncthreads drains vmcnt(0)
    // (publishes this tile) - implicit in its s_waitcnt.
    stageKV(kb0 + t * 64);
    __syncthreads();

    // Per 32-key group p: QK^T for j=2p,2p+1 -> exp -> pack pf8, then PV.
    // Interleaved per-p to keep pf8 liveness at 8 regs.
#pragma unroll
    for (int p = 0; p < 2; ++p) {
      union PK { hf16x2 h2[4]; f16x8 v; } pk;
#pragma unroll
      for (int jj = 0; jj < 2; ++jj) {
        const int j = p * 2 + jj;
        const int R = j * 16 + lm;
        const bf16x8 k0 = *(const bf16x8*)&sK[(R * 8 + (qd ^ (lm & 7))) * 8];
        const bf16x8 k1 = *(const bf16x8*)&sK[(R * 8 + ((4 + qd) ^ (lm & 7))) * 8];
        const float4 bj = *(const float4*)&sMB[t * 64 + p * 32 + qd * 8 + jj * 4];
        f32x4 t0 = (f32x4){bj.x, bj.y, bj.z, bj.w};
        __builtin_amdgcn_s_setprio(1);
        t0 = __builtin_amdgcn_mfma_f32_16x16x32_bf16(k0, qf[0], t0, 0, 0, 0);
        t0 = __builtin_amdgcn_mfma_f32_16x16x32_bf16(k1, qf[1], t0, 0, 0, 0);
        __builtin_amdgcn_s_setprio(0);
        const float p0 = EXP2(t0[0]);
        const float p1 = EXP2(t0[1]);
        const float p2 = EXP2(t0[2]);
        const float p3 = EXP2(t0[3]);
        lsum += (p0 + p1) + (p2 + p3);
        pk.h2[jj * 2] = __builtin_amdgcn_cvt_pkrtz(p0, p1);
        pk.h2[jj * 2 + 1] = __builtin_amdgcn_cvt_pkrtz(p2, p3);
      }
      const f16x8 pf8 = pk.v;
      // O^T += V-frag x P-frag; K=32 per mfma, b128 conflict-free V reads.
      __builtin_amdgcn_s_setprio(1);
#pragma unroll
      for (int dt = 0; dt < 4; ++dt) {
        const f16x8 vf =
            *(const f16x8*)&sV[(dt * 16 + lm) * 64 + ((p * 4 + qd) ^ (lm & 7)) * 8];
        Od[dt] = __builtin_amdgcn_mfma_f32_16x16x32_f16(vf, pf8, Od[dt], 0, 0, 0);
      }
      __builtin_amdgcn_s_setprio(0);
    }
    __syncthreads();  // all waves done reading sK/sV before next stage
  }

  float ls = lsum;
  ls += __shfl_xor(ls, 16);
  ls += __shfl_xor(ls, 32);
  if (qd == 0) Lp[(b * NHEAD + h) * SS + q0 + lm] = ls;
  // O^T C-layout: lane (qd,lm) holds q=lm, dims dt*16 + qd*4 + r
#pragma unroll
  for (int dt = 0; dt < 4; ++dt) {
    ushort4 u;
    u.x = f2bf(Od[dt][0]); u.y = f2bf(Od[dt][1]);
    u.z = f2bf(Od[dt][2]); u.w = f2bf(Od[dt][3]);
    *(ushort4*)&Op[(b * SS + q0 + lm) * EMBED + h * HDIM + dt * 16 + qd * 4] = u;
  }
}

extern "C" void kernel_launch(void* const* d_in, const int* in_sizes, int n_in,
                              void* d_out, int out_size, void* d_ws, size_t ws_size,
                              hipStream_t stream) {
  const float* x  = (const float*)d_in[0];
  const int* mask = (const int*)d_in[1];
  const float* Wq = (const float*)d_in[2];
  const float* bq = (const float*)d_in[3];
  const float* Wk = (const float*)d_in[4];
  const float* bk = (const float*)d_in[5];
  const float* Wv = (const float*)d_in[6];
  const float* bv = (const float*)d_in[7];
  const float* Wo = (const float*)d_in[8];
  const float* bo = (const float*)d_in[9];
  float* out = (float*)d_out;

  char* ws = (char*)d_ws;
  const size_t MB = 1024 * 1024;
  unsigned short* xb  = (unsigned short*)(ws);            // 8MB
  unsigned short* Wqb = (unsigned short*)(ws + 8 * MB);   // 2MB each
  unsigned short* Wkb = Wqb + 1024 * 1024;
  unsigned short* Wvb = Wkb + 1024 * 1024;
  unsigned short* Wob = Wvb + 1024 * 1024;                 // alive till gemm_out
  unsigned short* Qb  = (unsigned short*)(ws + 16 * MB);  // 8MB
  unsigned short* Kb  = (unsigned short*)(ws + 24 * MB);  // 8MB
  unsigned short* VTb = (unsigned short*)(ws + 32 * MB);  // 8MB (fp16)
  unsigned short* Opart = (unsigned short*)(ws + 40 * MB); // 2 x 8MB bf16
  float* mbb   = (float*)(ws + 56 * MB);                   // 16KB
  float* Lpart = (float*)(ws + 56 * MB + 64 * 1024);       // 2 x 256KB

  cvt5_kernel<<<8196, 256, 0, stream>>>(x, Wq, Wk, Wv, Wo, mask,
                                        xb, Wqb, Wkb, Wvb, Wob, mbb);
  gemm_qkv<<<dim3(256, 3), 256, 0, stream>>>(xb, Wqb, Wkb, Wvb, bq, bk, bv,
                                             Qb, Kb, VTb);
  attn_kernel<<<dim3(32, 16, 4), 256, 0, stream>>>(Qb, Kb, VTb, mbb,
                                                   Opart, Lpart);
  gemm_out<<<256, 256, 0, stream>>>(Wob, Opart, Lpart, bo, out);
}

// Round 11
// 207.006 us; speedup vs baseline: 1.1332x; 1.0964x over previous
//
#include <hip/hip_runtime.h>

#define EMBED 1024
#define NHEAD 16
#define HDIM  64
#define BB    2
#define SS    2048

typedef __bf16 bf16x8 __attribute__((ext_vector_type(8)));
typedef float  f32x4  __attribute__((ext_vector_type(4)));
typedef _Float16 f16x8 __attribute__((ext_vector_type(8)));
typedef __fp16 hf16x2 __attribute__((ext_vector_type(2)));

#if defined(__has_builtin)
#if __has_builtin(__builtin_amdgcn_exp2f)
#define EXP2(x) __builtin_amdgcn_exp2f(x)
#else
#define EXP2(x) exp2f(x)
#endif
#else
#define EXP2(x) exp2f(x)
#endif

__device__ __forceinline__ unsigned short f2bf(float f) {
  union { float f; unsigned u; } v; v.f = f;
  unsigned r = v.u + 0x7fffu + ((v.u >> 16) & 1u);
  return (unsigned short)(r >> 16);
}

__device__ __forceinline__ float bf2f(unsigned short u) {
  union { unsigned u; float f; } v; v.u = ((unsigned)u) << 16;
  return v.f;
}

__device__ __forceinline__ unsigned short f2h(float f) {
  union { _Float16 h; unsigned short u; } t;
  t.h = (_Float16)f;
  return t.u;
}

__device__ __forceinline__ void g2l16(const unsigned short* g, unsigned short* l) {
  __builtin_amdgcn_global_load_lds(
      (const __attribute__((address_space(1))) unsigned int*)g,
      (__attribute__((address_space(3))) unsigned int*)l, 16, 0, 0);
}

// ------- fused fp32->bf16 convert of x + 4 weights, + maskbias build -------
__global__ __launch_bounds__(256)
void cvt5_kernel(const float* __restrict__ x,  const float* __restrict__ Wq,
                 const float* __restrict__ Wk, const float* __restrict__ Wv,
                 const float* __restrict__ Wo, const int* __restrict__ mask,
                 unsigned short* __restrict__ xb,  unsigned short* __restrict__ Wqb,
                 unsigned short* __restrict__ Wkb, unsigned short* __restrict__ Wvb,
                 unsigned short* __restrict__ Wob, float* __restrict__ mbias) {
  const int i = blockIdx.x * 256 + threadIdx.x;
  if (i < (1 << 21)) {
    const float* src;
    unsigned short* dst;
    int j;
    if (i < (1 << 20)) {
      src = x; dst = xb; j = i;
    } else {
      const int t = i - (1 << 20);
      const int r = t >> 18;
      j = t & ((1 << 18) - 1);
      src = (r == 0) ? Wq : (r == 1) ? Wk : (r == 2) ? Wv : Wo;
      dst = (r == 0) ? Wqb : (r == 1) ? Wkb : (r == 2) ? Wvb : Wob;
    }
    const float4 f = ((const float4*)src)[j];
    ushort4 u;
    u.x = f2bf(f.x); u.y = f2bf(f.y); u.z = f2bf(f.z); u.w = f2bf(f.w);
    ((ushort4*)dst)[j] = u;
  } else {
    const int j = i - (1 << 21);  // 0..1023 int4 groups of mask
    const int4 m = ((const int4*)mask)[j];
    float4 o;
    o.x = m.x ? 0.f : -1e30f; o.y = m.y ? 0.f : -1e30f;
    o.z = m.z ? 0.f : -1e30f; o.w = m.w ? 0.f : -1e30f;
    ((float4*)mbias)[j] = o;
  }
}

// ------- shared GEMM core: C[m][n] = sum_k A[m][k]*Bm[n][k] (128x128) -----
template <typename EpiFn>
__device__ __forceinline__
void gemm_core(const unsigned short* __restrict__ A,
               const unsigned short* __restrict__ Bm,
               int m0, int n0, EpiFn epi) {
  __shared__ unsigned short sA[128 * 64];
  __shared__ unsigned short sB[128 * 64];
  const int tid = threadIdx.x;
  const int l  = tid & 63;
  const int w  = tid >> 6;
  const int lm = l & 15;
  const int qd = l >> 4;
  const int wm = w & 1;
  const int wn = w >> 1;

  f32x4 acc[4][4];
#pragma unroll
  for (int i = 0; i < 4; ++i)
#pragma unroll
    for (int j = 0; j < 4; ++j) acc[i][j] = (f32x4){0.f, 0.f, 0.f, 0.f};

  for (int k0 = 0; k0 < EMBED; k0 += 64) {
#pragma unroll
    for (int i = 0; i < 4; ++i) {
      const int t = i * 256 + tid;
      const int r = t >> 3;
      const int c = (t & 7) ^ (r & 7);
      g2l16(A + (m0 + r) * EMBED + k0 + c * 8, &sA[(i * 256 + (w << 6)) * 8]);
      g2l16(Bm + (n0 + r) * EMBED + k0 + c * 8, &sB[(i * 256 + (w << 6)) * 8]);
    }
    __syncthreads();
#pragma unroll
    for (int kk = 0; kk < 2; ++kk) {
      bf16x8 af[4], bfr[4];
#pragma unroll
      for (int mi = 0; mi < 4; ++mi) {
        const int R = wm * 64 + mi * 16 + lm;
        const int ch = R * 8 + (((kk << 2) + qd) ^ (R & 7));
        af[mi] = *(const bf16x8*)&sA[ch * 8];
      }
#pragma unroll
      for (int ni = 0; ni < 4; ++ni) {
        const int R = wn * 64 + ni * 16 + lm;
        const int ch = R * 8 + (((kk << 2) + qd) ^ (R & 7));
        bfr[ni] = *(const bf16x8*)&sB[ch * 8];
      }
#pragma unroll
      for (int mi = 0; mi < 4; ++mi)
#pragma unroll
        for (int ni = 0; ni < 4; ++ni)
          acc[mi][ni] = __builtin_amdgcn_mfma_f32_16x16x32_bf16(
              af[mi], bfr[ni], acc[mi][ni], 0, 0, 0);
    }
    __syncthreads();
  }

#pragma unroll
  for (int mi = 0; mi < 4; ++mi)
#pragma unroll
    for (int ni = 0; ni < 4; ++ni) {
      const int mb = m0 + wm * 64 + mi * 16 + qd * 4;  // rows mb..mb+3
      const int n  = n0 + wn * 64 + ni * 16 + lm;
      epi(acc[mi][ni], mb, n);
    }
}

// supertile decode for L2 locality: 16 consecutive blocks = 2a x 8b tile grp
__device__ __forceinline__ void decode_tile(int flat, int& a0, int& b0) {
  const int sub = flat & 15;
  const int g = flat >> 4;           // 0..15
  a0 = ((g >> 2) * 2 + (sub >> 3));  // 0..7  (feature dim / 128)
  b0 = ((g & 3) * 8 + (sub & 7));    // 0..31 (token dim / 128)
}

// ------- fused Q/K/V projection -------
// z=0: Q = Wq·x^T ->(b,h,s,d) bf16, pre-scaled by (1/8)*log2(e)
// z=1: K = Wk·x^T ->(b,h,s,d) bf16, tokens PERMUTED within 32-groups so the
//      attn S^T lane layout becomes PV-contiguous: token w sits at row
//      ((w>>2)&1)*16 + ((w>>3)&3)*4 + (w&3) of its 32-block.
// z=2: V = x·Wv^T ->(b,h,d,s) fp16 (transposed, for PV MFMA)
__global__ __launch_bounds__(256)
void gemm_qkv(const unsigned short* __restrict__ xb,
              const unsigned short* __restrict__ Wqb,
              const unsigned short* __restrict__ Wkb,
              const unsigned short* __restrict__ Wvb,
              const float* __restrict__ bq, const float* __restrict__ bk,
              const float* __restrict__ bv,
              unsigned short* __restrict__ Qb, unsigned short* __restrict__ Kb,
              unsigned short* __restrict__ VTb) {
  const int z = blockIdx.y;
  int a0, b0;
  decode_tile(blockIdx.x, a0, b0);
  if (z < 2) {
    const unsigned short* A = z ? Wkb : Wqb;
    const float* bias = z ? bk : bq;
    unsigned short* O = z ? Kb : Qb;
    const float scale = z ? 1.0f : 0.125f * 1.4426950408889634f;
    gemm_core(A, xb, a0 * 128, b0 * 128, [&](const f32x4& v, int mb, int n) {
      const float4 bvv = *(const float4*)&bias[mb];
      const int h = mb >> 6, d0 = mb & 63;
      const int b = n >> 11, s = n & 2047;
      int sw = s;
      if (z == 1)
        sw = (s & ~31) | (((s >> 2) & 1) << 4) | (((s >> 3) & 3) << 2) | (s & 3);
      ushort4 u;
      u.x = f2bf((v.x + bvv.x) * scale); u.y = f2bf((v.y + bvv.y) * scale);
      u.z = f2bf((v.z + bvv.z) * scale); u.w = f2bf((v.w + bvv.w) * scale);
      *(ushort4*)&O[(((b * NHEAD + h) * SS) + sw) * HDIM + d0] = u;
    });
  } else {
    gemm_core(xb, Wvb, b0 * 128, a0 * 128, [&](const f32x4& v, int mb, int n) {
      const float bvv = bv[n];
      const int b = mb >> 11, s = mb & 2047;
      const int h = n >> 6, d = n & 63;
      ushort4 u;
      u.x = f2h(v.x + bvv); u.y = f2h(v.y + bvv);
      u.z = f2h(v.z + bvv); u.w = f2h(v.w + bvv);
      *(ushort4*)&VTb[(((b * NHEAD + h) * HDIM) + d) * SS + s] = u;
    });
  }
}

// ------- output projection: 64x128 tile, 512 blocks = 2 blocks/CU ----------
// Round-9 lesson: gemm_out at 256 blocks = 1 block/CU = 1 wave/SIMD is the
// most latency-exposed kernel in the pipeline (any staging latency lands on
// the wall clock). 64(m)x128(n) tile doubles the grid -> 2 blocks/CU, LDS
// 24KB, acc[2][4]=32 VGPR. Same staging swizzle / fragment idioms as the
// proven gemm_core. m-fastest block order: the 16 m-tiles sharing one
// B-panel (256KB of Ob) are dispatch-adjacent for L2 reuse.
__global__ __launch_bounds__(256)
void gemm_out(const unsigned short* __restrict__ Wob,
              const unsigned short* __restrict__ Ob,
              const float* __restrict__ bo, float* __restrict__ out) {
  __shared__ unsigned short sA[64 * 64];   // 8KB
  __shared__ unsigned short sB[128 * 64];  // 16KB
  const int m0 = (blockIdx.x & 15) * 64;   // feature tile (16)
  const int n0 = (blockIdx.x >> 4) * 128;  // token tile (32)
  const int tid = threadIdx.x;
  const int l  = tid & 63;
  const int w  = tid >> 6;
  const int lm = l & 15;
  const int qd = l >> 4;
  const int wm = w & 1;
  const int wn = w >> 1;

  f32x4 acc[2][4];
#pragma unroll
  for (int i = 0; i < 2; ++i)
#pragma unroll
    for (int j = 0; j < 4; ++j) acc[i][j] = (f32x4){0.f, 0.f, 0.f, 0.f};

  for (int k0 = 0; k0 < EMBED; k0 += 64) {
#pragma unroll
    for (int i = 0; i < 2; ++i) {  // A: 64 rows = 2 rounds
      const int t = i * 256 + tid;
      const int r = t >> 3;
      const int c = (t & 7) ^ (r & 7);
      g2l16(Wob + (m0 + r) * EMBED + k0 + c * 8, &sA[(i * 256 + (w << 6)) * 8]);
    }
#pragma unroll
    for (int i = 0; i < 4; ++i) {  // B: 128 rows = 4 rounds
      const int t = i * 256 + tid;
      const int r = t >> 3;
      const int c = (t & 7) ^ (r & 7);
      g2l16(Ob + (n0 + r) * EMBED + k0 + c * 8, &sB[(i * 256 + (w << 6)) * 8]);
    }
    __syncthreads();
#pragma unroll
    for (int kk = 0; kk < 2; ++kk) {
      bf16x8 af[2], bfr[4];
#pragma unroll
      for (int mi = 0; mi < 2; ++mi) {
        const int R = wm * 32 + mi * 16 + lm;
        const int ch = R * 8 + (((kk << 2) + qd) ^ (R & 7));
        af[mi] = *(const bf16x8*)&sA[ch * 8];
      }
#pragma unroll
      for (int ni = 0; ni < 4; ++ni) {
        const int R = wn * 64 + ni * 16 + lm;
        const int ch = R * 8 + (((kk << 2) + qd) ^ (R & 7));
        bfr[ni] = *(const bf16x8*)&sB[ch * 8];
      }
#pragma unroll
      for (int mi = 0; mi < 2; ++mi)
#pragma unroll
        for (int ni = 0; ni < 4; ++ni)
          acc[mi][ni] = __builtin_amdgcn_mfma_f32_16x16x32_bf16(
              af[mi], bfr[ni], acc[mi][ni], 0, 0, 0);
    }
    __syncthreads();
  }

#pragma unroll
  for (int mi = 0; mi < 2; ++mi)
#pragma unroll
    for (int ni = 0; ni < 4; ++ni) {
      const int mb = m0 + wm * 32 + mi * 16 + qd * 4;
      const int n  = n0 + wn * 64 + ni * 16 + lm;
      const float4 bvv = *(const float4*)&bo[mb];
      float4 o;
      o.x = acc[mi][ni][0] + bvv.x; o.y = acc[mi][ni][1] + bvv.y;
      o.z = acc[mi][ni][2] + bvv.z; o.w = acc[mi][ni][3] + bvv.w;
      *(float4*)&out[n * EMBED + mb] = o;
    }
}

// ------- flash attention, key-split x2, 16 q per wave, 8 blocks/CU ---------
// (round-6 verified version: 51.4us, VGPR 40, zero conflicts)
// grid (32 qtiles, 16 heads, b*2+split). Each block: 4 waves x 16 q,
// 16 64-key tiles, single-buffered K/V (20480B LDS = 8 blocks/CU capacity).
__global__ __launch_bounds__(256, 6)
void attn_kernel(const unsigned short* __restrict__ Q,
                 const unsigned short* __restrict__ K,
                 const unsigned short* __restrict__ VT,
                 const float* __restrict__ mbias,
                 unsigned short* __restrict__ Opart,
                 float* __restrict__ Lpart) {
  __shared__ unsigned short sK[64 * 64];  // bf16, row=key, chunk-swizzled
  __shared__ unsigned short sV[64 * 64];  // fp16, row=dim, chunk-swizzled
  __shared__ float sMB[SS / 2];           // mask bias for this split (4KB)
  const int tid = threadIdx.x;
  const int l = tid & 63, w = tid >> 6;
  const int lm = l & 15, qd = l >> 4;
  const int b = blockIdx.z & 1, sp = blockIdx.z >> 1, h = blockIdx.y;
  const int q0 = blockIdx.x * 64 + w * 16;  // wave: q0 .. q0+15
  const unsigned short* Qh = Q + ((b * NHEAD + h) * SS) * HDIM;
  const unsigned short* Kh = K + ((b * NHEAD + h) * SS) * HDIM;
  const unsigned short* Vh = VT + ((b * NHEAD + h) * HDIM) * SS;
  const float* mb = mbias + b * SS + sp * (SS / 2);
  unsigned short* Op = Opart + sp * (BB * SS * EMBED);
  float* Lp = Lpart + sp * (BB * NHEAD * SS);
  const int kb0 = sp * (SS / 2);

  bf16x8 qf[2];
  qf[0] = *(const bf16x8*)&Qh[(q0 + lm) * HDIM + qd * 8];
  qf[1] = *(const bf16x8*)&Qh[(q0 + lm) * HDIM + 32 + qd * 8];

  auto stageKV = [&](int kb) {
#pragma unroll
    for (int i = 0; i < 2; ++i) {
      const int t = i * 256 + tid;
      const int r = t >> 3;
      const int c = (t & 7) ^ (r & 7);
      g2l16(Kh + (kb + r) * HDIM + c * 8, &sK[(i * 256 + (w << 6)) * 8]);
      g2l16(Vh + r * SS + kb + c * 8, &sV[(i * 256 + (w << 6)) * 8]);
    }
  };

  // one-time mask-bias stage (4KB: 256 lanes x 16B)
  g2l16((const unsigned short*)(mb + tid * 4), (unsigned short*)&sMB[w * 256]);

  f32x4 Od[4];
#pragma unroll
  for (int i = 0; i < 4; ++i) Od[i] = (f32x4){0.f, 0.f, 0.f, 0.f};
  float lsum = 0.f;

  const int NT = (SS / 2) / 64;
  for (int t = 0; t < NT; ++t) {
    // Overwrite of sK/sV is safe: trailing barrier of iter t-1 guarantees
    // all waves finished reading. Leading __syncthreads drains vmcnt(0)
    // (publishes this tile) - implicit in its s_waitcnt.
    stageKV(kb0 + t * 64);
    __syncthreads();

    // Per 32-key group p: QK^T for j=2p,2p+1 -> exp -> pack pf8, then PV.
    // Interleaved per-p to keep pf8 liveness at 8 regs.
#pragma unroll
    for (int p = 0; p < 2; ++p) {
      union PK { hf16x2 h2[4]; f16x8 v; } pk;
#pragma unroll
      for (int jj = 0; jj < 2; ++jj) {
        const int j = p * 2 + jj;
        const int R = j * 16 + lm;
        const bf16x8 k0 = *(const bf16x8*)&sK[(R * 8 + (qd ^ (lm & 7))) * 8];
        const bf16x8 k1 = *(const bf16x8*)&sK[(R * 8 + ((4 + qd) ^ (lm & 7))) * 8];
        const float4 bj = *(const float4*)&sMB[t * 64 + p * 32 + qd * 8 + jj * 4];
        f32x4 t0 = (f32x4){bj.x, bj.y, bj.z, bj.w};
        __builtin_amdgcn_s_setprio(1);
        t0 = __builtin_amdgcn_mfma_f32_16x16x32_bf16(k0, qf[0], t0, 0, 0, 0);
        t0 = __builtin_amdgcn_mfma_f32_16x16x32_bf16(k1, qf[1], t0, 0, 0, 0);
        __builtin_amdgcn_s_setprio(0);
        const float p0 = EXP2(t0[0]);
        const float p1 = EXP2(t0[1]);
        const float p2 = EXP2(t0[2]);
        const float p3 = EXP2(t0[3]);
        lsum += (p0 + p1) + (p2 + p3);
        pk.h2[jj * 2] = __builtin_amdgcn_cvt_pkrtz(p0, p1);
        pk.h2[jj * 2 + 1] = __builtin_amdgcn_cvt_pkrtz(p2, p3);
      }
      const f16x8 pf8 = pk.v;
      // O^T += V-frag x P-frag; K=32 per mfma, b128 conflict-free V reads.
      __builtin_amdgcn_s_setprio(1);
#pragma unroll
      for (int dt = 0; dt < 4; ++dt) {
        const f16x8 vf =
            *(const f16x8*)&sV[(dt * 16 + lm) * 64 + ((p * 4 + qd) ^ (lm & 7)) * 8];
        Od[dt] = __builtin_amdgcn_mfma_f32_16x16x32_f16(vf, pf8, Od[dt], 0, 0, 0);
      }
      __builtin_amdgcn_s_setprio(0);
    }
    __syncthreads();  // all waves done reading sK/sV before next stage
  }

  float ls = lsum;
  ls += __shfl_xor(ls, 16);
  ls += __shfl_xor(ls, 32);
  if (qd == 0) Lp[(b * NHEAD + h) * SS + q0 + lm] = ls;
  // O^T C-layout: lane (qd,lm) holds q=lm, dims dt*16 + qd*4 + r
#pragma unroll
  for (int dt = 0; dt < 4; ++dt) {
    ushort4 u;
    u.x = f2bf(Od[dt][0]); u.y = f2bf(Od[dt][1]);
    u.z = f2bf(Od[dt][2]); u.w = f2bf(Od[dt][3]);
    *(ushort4*)&Op[(b * SS + q0 + lm) * EMBED + h * HDIM + dt * 16 + qd * 4] = u;
  }
}

// ------- combine: Ob = (P0 + P1) / (l0 + l1), bf16 out -------
__global__ __launch_bounds__(256)
void combine_kernel(const unsigned short* __restrict__ Opart,
                    const float* __restrict__ Lpart,
                    unsigned short* __restrict__ Ob) {
  const int i = blockIdx.x * 256 + threadIdx.x;  // per 8 elems
  const int base = i * 8;
  const int token = base >> 10;       // 0..4095
  const int h = (base >> 6) & 15;
  const int b = token >> 11, q = token & 2047;
  const int lidx = (b * NHEAD + h) * SS + q;
  const float ls = Lpart[lidx] + Lpart[BB * NHEAD * SS + lidx];
  const float rinv = 1.f / ls;
  const ushort4* p0 = (const ushort4*)&Opart[base];
  const ushort4* p1 = (const ushort4*)&Opart[BB * SS * EMBED + base];
  ushort4 o[2];
#pragma unroll
  for (int k = 0; k < 2; ++k) {
    const ushort4 a = p0[k], c = p1[k];
    o[k].x = f2bf((bf2f(a.x) + bf2f(c.x)) * rinv);
    o[k].y = f2bf((bf2f(a.y) + bf2f(c.y)) * rinv);
    o[k].z = f2bf((bf2f(a.z) + bf2f(c.z)) * rinv);
    o[k].w = f2bf((bf2f(a.w) + bf2f(c.w)) * rinv);
  }
  *(ushort4*)&Ob[base] = o[0];
  *(ushort4*)&Ob[base + 4] = o[1];
}

extern "C" void kernel_launch(void* const* d_in, const int* in_sizes, int n_in,
                              void* d_out, int out_size, void* d_ws, size_t ws_size,
                              hipStream_t stream) {
  const float* x  = (const float*)d_in[0];
  const int* mask = (const int*)d_in[1];
  const float* Wq = (const float*)d_in[2];
  const float* bq = (const float*)d_in[3];
  const float* Wk = (const float*)d_in[4];
  const float* bk = (const float*)d_in[5];
  const float* Wv = (const float*)d_in[6];
  const float* bv = (const float*)d_in[7];
  const float* Wo = (const float*)d_in[8];
  const float* bo = (const float*)d_in[9];
  float* out = (float*)d_out;

  char* ws = (char*)d_ws;
  const size_t MB = 1024 * 1024;
  // xb [0,8MB) dead after gemm_qkv -> Ob reuses it (combine writes, gemm_out reads)
  unsigned short* xb  = (unsigned short*)(ws);
  unsigned short* Ob  = (unsigned short*)(ws);
  unsigned short* Wqb = (unsigned short*)(ws + 8 * MB);   // 2MB each
  unsigned short* Wkb = Wqb + 1024 * 1024;
  unsigned short* Wvb = Wkb + 1024 * 1024;
  unsigned short* Wob = Wvb + 1024 * 1024;                 // alive till gemm_out
  unsigned short* Qb  = (unsigned short*)(ws + 16 * MB);  // 8MB
  unsigned short* Kb  = (unsigned short*)(ws + 24 * MB);  // 8MB
  unsigned short* VTb = (unsigned short*)(ws + 32 * MB);  // 8MB (fp16)
  unsigned short* Opart = (unsigned short*)(ws + 40 * MB); // 2 x 8MB bf16
  float* mbb   = (float*)(ws + 56 * MB);                   // 16KB
  float* Lpart = (float*)(ws + 56 * MB + 64 * 1024);       // 2 x 256KB

  cvt5_kernel<<<8196, 256, 0, stream>>>(x, Wq, Wk, Wv, Wo, mask,
                                        xb, Wqb, Wkb, Wvb, Wob, mbb);
  gemm_qkv<<<dim3(256, 3), 256, 0, stream>>>(xb, Wqb, Wkb, Wvb, bq, bk, bv,
                                             Qb, Kb, VTb);
  attn_kernel<<<dim3(32, 16, 4), 256, 0, stream>>>(Qb, Kb, VTb, mbb,
                                                   Opart, Lpart);
  combine_kernel<<<2048, 256, 0, stream>>>(Opart, Lpart, Ob);
  gemm_out<<<512, 256, 0, stream>>>(Wob, Ob, bo, out);
}

// Round 12
// 205.430 us; speedup vs baseline: 1.1419x; 1.0077x over previous
//
#include <hip/hip_runtime.h>

#define EMBED 1024
#define NHEAD 16
#define HDIM  64
#define BB    2
#define SS    2048

typedef __bf16 bf16x8 __attribute__((ext_vector_type(8)));
typedef float  f32x4  __attribute__((ext_vector_type(4)));
typedef _Float16 f16x8 __attribute__((ext_vector_type(8)));
typedef __fp16 hf16x2 __attribute__((ext_vector_type(2)));

#if defined(__has_builtin)
#if __has_builtin(__builtin_amdgcn_exp2f)
#define EXP2(x) __builtin_amdgcn_exp2f(x)
#else
#define EXP2(x) exp2f(x)
#endif
#else
#define EXP2(x) exp2f(x)
#endif

__device__ __forceinline__ unsigned short f2bf(float f) {
  union { float f; unsigned u; } v; v.f = f;
  unsigned r = v.u + 0x7fffu + ((v.u >> 16) & 1u);
  return (unsigned short)(r >> 16);
}

__device__ __forceinline__ float bf2f(unsigned short u) {
  union { unsigned u; float f; } v; v.u = ((unsigned)u) << 16;
  return v.f;
}

__device__ __forceinline__ unsigned short f2h(float f) {
  union { _Float16 h; unsigned short u; } t;
  t.h = (_Float16)f;
  return t.u;
}

__device__ __forceinline__ void g2l16(const unsigned short* g, unsigned short* l) {
  __builtin_amdgcn_global_load_lds(
      (const __attribute__((address_space(1))) unsigned int*)g,
      (__attribute__((address_space(3))) unsigned int*)l, 16, 0, 0);
}

// ------- fused fp32->bf16 convert of x + 4 weights, + maskbias build -------
__global__ __launch_bounds__(256)
void cvt5_kernel(const float* __restrict__ x,  const float* __restrict__ Wq,
                 const float* __restrict__ Wk, const float* __restrict__ Wv,
                 const float* __restrict__ Wo, const int* __restrict__ mask,
                 unsigned short* __restrict__ xb,  unsigned short* __restrict__ Wqb,
                 unsigned short* __restrict__ Wkb, unsigned short* __restrict__ Wvb,
                 unsigned short* __restrict__ Wob, float* __restrict__ mbias) {
  const int i = blockIdx.x * 256 + threadIdx.x;
  if (i < (1 << 21)) {
    const float* src;
    unsigned short* dst;
    int j;
    if (i < (1 << 20)) {
      src = x; dst = xb; j = i;
    } else {
      const int t = i - (1 << 20);
      const int r = t >> 18;
      j = t & ((1 << 18) - 1);
      src = (r == 0) ? Wq : (r == 1) ? Wk : (r == 2) ? Wv : Wo;
      dst = (r == 0) ? Wqb : (r == 1) ? Wkb : (r == 2) ? Wvb : Wob;
    }
    const float4 f = ((const float4*)src)[j];
    ushort4 u;
    u.x = f2bf(f.x); u.y = f2bf(f.y); u.z = f2bf(f.z); u.w = f2bf(f.w);
    ((ushort4*)dst)[j] = u;
  } else {
    const int j = i - (1 << 21);  // 0..1023 int4 groups of mask
    const int4 m = ((const int4*)mask)[j];
    float4 o;
    o.x = m.x ? 0.f : -1e30f; o.y = m.y ? 0.f : -1e30f;
    o.z = m.z ? 0.f : -1e30f; o.w = m.w ? 0.f : -1e30f;
    ((float4*)mbias)[j] = o;
  }
}

// ------- shared GEMM core: C[m][n] = sum_k A[m][k]*Bm[n][k] (128x128) -----
template <typename EpiFn>
__device__ __forceinline__
void gemm_core(const unsigned short* __restrict__ A,
               const unsigned short* __restrict__ Bm,
               int m0, int n0, EpiFn epi) {
  __shared__ unsigned short sA[128 * 64];
  __shared__ unsigned short sB[128 * 64];
  const int tid = threadIdx.x;
  const int l  = tid & 63;
  const int w  = tid >> 6;
  const int lm = l & 15;
  const int qd = l >> 4;
  const int wm = w & 1;
  const int wn = w >> 1;

  f32x4 acc[4][4];
#pragma unroll
  for (int i = 0; i < 4; ++i)
#pragma unroll
    for (int j = 0; j < 4; ++j) acc[i][j] = (f32x4){0.f, 0.f, 0.f, 0.f};

  for (int k0 = 0; k0 < EMBED; k0 += 64) {
#pragma unroll
    for (int i = 0; i < 4; ++i) {
      const int t = i * 256 + tid;
      const int r = t >> 3;
      const int c = (t & 7) ^ (r & 7);
      g2l16(A + (m0 + r) * EMBED + k0 + c * 8, &sA[(i * 256 + (w << 6)) * 8]);
      g2l16(Bm + (n0 + r) * EMBED + k0 + c * 8, &sB[(i * 256 + (w << 6)) * 8]);
    }
    __syncthreads();
#pragma unroll
    for (int kk = 0; kk < 2; ++kk) {
      bf16x8 af[4], bfr[4];
#pragma unroll
      for (int mi = 0; mi < 4; ++mi) {
        const int R = wm * 64 + mi * 16 + lm;
        const int ch = R * 8 + (((kk << 2) + qd) ^ (R & 7));
        af[mi] = *(const bf16x8*)&sA[ch * 8];
      }
#pragma unroll
      for (int ni = 0; ni < 4; ++ni) {
        const int R = wn * 64 + ni * 16 + lm;
        const int ch = R * 8 + (((kk << 2) + qd) ^ (R & 7));
        bfr[ni] = *(const bf16x8*)&sB[ch * 8];
      }
#pragma unroll
      for (int mi = 0; mi < 4; ++mi)
#pragma unroll
        for (int ni = 0; ni < 4; ++ni)
          acc[mi][ni] = __builtin_amdgcn_mfma_f32_16x16x32_bf16(
              af[mi], bfr[ni], acc[mi][ni], 0, 0, 0);
    }
    __syncthreads();
  }

#pragma unroll
  for (int mi = 0; mi < 4; ++mi)
#pragma unroll
    for (int ni = 0; ni < 4; ++ni) {
      const int mb = m0 + wm * 64 + mi * 16 + qd * 4;  // rows mb..mb+3
      const int n  = n0 + wn * 64 + ni * 16 + lm;
      epi(acc[mi][ni], mb, n);
    }
}

// supertile decode for L2 locality: 16 consecutive blocks = 2a x 8b tile grp
__device__ __forceinline__ void decode_tile(int flat, int& a0, int& b0) {
  const int sub = flat & 15;
  const int g = flat >> 4;           // 0..15
  a0 = ((g >> 2) * 2 + (sub >> 3));  // 0..7  (feature dim / 128)
  b0 = ((g & 3) * 8 + (sub & 7));    // 0..31 (token dim / 128)
}

// ------- fused Q/K/V projection -------
// z=0: Q = Wq·x^T ->(b,h,s,d) bf16, pre-scaled by (1/8)*log2(e)
// z=1: K = Wk·x^T ->(b,h,s,d) bf16, tokens PERMUTED within 32-groups so the
//      attn S^T lane layout becomes PV-contiguous: token w sits at row
//      ((w>>2)&1)*16 + ((w>>3)&3)*4 + (w&3) of its 32-block.
// z=2: V = x·Wv^T ->(b,h,d,s) fp16 (transposed, for PV MFMA)
__global__ __launch_bounds__(256)
void gemm_qkv(const unsigned short* __restrict__ xb,
              const unsigned short* __restrict__ Wqb,
              const unsigned short* __restrict__ Wkb,
              const unsigned short* __restrict__ Wvb,
              const float* __restrict__ bq, const float* __restrict__ bk,
              const float* __restrict__ bv,
              unsigned short* __restrict__ Qb, unsigned short* __restrict__ Kb,
              unsigned short* __restrict__ VTb) {
  const int z = blockIdx.y;
  int a0, b0;
  decode_tile(blockIdx.x, a0, b0);
  if (z < 2) {
    const unsigned short* A = z ? Wkb : Wqb;
    const float* bias = z ? bk : bq;
    unsigned short* O = z ? Kb : Qb;
    const float scale = z ? 1.0f : 0.125f * 1.4426950408889634f;
    gemm_core(A, xb, a0 * 128, b0 * 128, [&](const f32x4& v, int mb, int n) {
      const float4 bvv = *(const float4*)&bias[mb];
      const int h = mb >> 6, d0 = mb & 63;
      const int b = n >> 11, s = n & 2047;
      int sw = s;
      if (z == 1)
        sw = (s & ~31) | (((s >> 2) & 1) << 4) | (((s >> 3) & 3) << 2) | (s & 3);
      ushort4 u;
      u.x = f2bf((v.x + bvv.x) * scale); u.y = f2bf((v.y + bvv.y) * scale);
      u.z = f2bf((v.z + bvv.z) * scale); u.w = f2bf((v.w + bvv.w) * scale);
      *(ushort4*)&O[(((b * NHEAD + h) * SS) + sw) * HDIM + d0] = u;
    });
  } else {
    gemm_core(xb, Wvb, b0 * 128, a0 * 128, [&](const f32x4& v, int mb, int n) {
      const float bvv = bv[n];
      const int b = mb >> 11, s = mb & 2047;
      const int h = n >> 6, d = n & 63;
      ushort4 u;
      u.x = f2h(v.x + bvv); u.y = f2h(v.y + bvv);
      u.z = f2h(v.z + bvv); u.w = f2h(v.w + bvv);
      *(ushort4*)&VTb[(((b * NHEAD + h) * HDIM) + d) * SS + s] = u;
    });
  }
}

// ------- output projection: 64x128 tile, 512 blocks = 2 blocks/CU ----------
__global__ __launch_bounds__(256)
void gemm_out(const unsigned short* __restrict__ Wob,
              const unsigned short* __restrict__ Ob,
              const float* __restrict__ bo, float* __restrict__ out) {
  __shared__ unsigned short sA[64 * 64];   // 8KB
  __shared__ unsigned short sB[128 * 64];  // 16KB
  const int m0 = (blockIdx.x & 15) * 64;   // feature tile (16)
  const int n0 = (blockIdx.x >> 4) * 128;  // token tile (32)
  const int tid = threadIdx.x;
  const int l  = tid & 63;
  const int w  = tid >> 6;
  const int lm = l & 15;
  const int qd = l >> 4;
  const int wm = w & 1;
  const int wn = w >> 1;

  f32x4 acc[2][4];
#pragma unroll
  for (int i = 0; i < 2; ++i)
#pragma unroll
    for (int j = 0; j < 4; ++j) acc[i][j] = (f32x4){0.f, 0.f, 0.f, 0.f};

  for (int k0 = 0; k0 < EMBED; k0 += 64) {
#pragma unroll
    for (int i = 0; i < 2; ++i) {  // A: 64 rows = 2 rounds
      const int t = i * 256 + tid;
      const int r = t >> 3;
      const int c = (t & 7) ^ (r & 7);
      g2l16(Wob + (m0 + r) * EMBED + k0 + c * 8, &sA[(i * 256 + (w << 6)) * 8]);
    }
#pragma unroll
    for (int i = 0; i < 4; ++i) {  // B: 128 rows = 4 rounds
      const int t = i * 256 + tid;
      const int r = t >> 3;
      const int c = (t & 7) ^ (r & 7);
      g2l16(Ob + (n0 + r) * EMBED + k0 + c * 8, &sB[(i * 256 + (w << 6)) * 8]);
    }
    __syncthreads();
#pragma unroll
    for (int kk = 0; kk < 2; ++kk) {
      bf16x8 af[2], bfr[4];
#pragma unroll
      for (int mi = 0; mi < 2; ++mi) {
        const int R = wm * 32 + mi * 16 + lm;
        const int ch = R * 8 + (((kk << 2) + qd) ^ (R & 7));
        af[mi] = *(const bf16x8*)&sA[ch * 8];
      }
#pragma unroll
      for (int ni = 0; ni < 4; ++ni) {
        const int R = wn * 64 + ni * 16 + lm;
        const int ch = R * 8 + (((kk << 2) + qd) ^ (R & 7));
        bfr[ni] = *(const bf16x8*)&sB[ch * 8];
      }
#pragma unroll
      for (int mi = 0; mi < 2; ++mi)
#pragma unroll
        for (int ni = 0; ni < 4; ++ni)
          acc[mi][ni] = __builtin_amdgcn_mfma_f32_16x16x32_bf16(
              af[mi], bfr[ni], acc[mi][ni], 0, 0, 0);
    }
    __syncthreads();
  }

#pragma unroll
  for (int mi = 0; mi < 2; ++mi)
#pragma unroll
    for (int ni = 0; ni < 4; ++ni) {
      const int mb = m0 + wm * 32 + mi * 16 + qd * 4;
      const int n  = n0 + wn * 64 + ni * 16 + lm;
      const float4 bvv = *(const float4*)&bo[mb];
      float4 o;
      o.x = acc[mi][ni][0] + bvv.x; o.y = acc[mi][ni][1] + bvv.y;
      o.z = acc[mi][ni][2] + bvv.z; o.w = acc[mi][ni][3] + bvv.w;
      *(float4*)&out[n * EMBED + mb] = o;
    }
}

// ------- flash attention, key-split x2, 16 q per wave, 8 blocks/CU ---------
// (round-6 compute, unchanged) + T1 XCD-aware block swizzle: grid flattened
// to 2048 and remapped so each XCD's round-robin share (bid%8) becomes a
// CONTIGUOUS logical range = 8 complete (head,b,split) K/V panels (8 x
// 256KB = 2MB < 4MB per-XCD L2). Default mapping scattered the 32 q-tile
// blocks sharing each panel across all 8 XCDs -> 3x K/V over-fetch
// (FETCH 71.8MB vs ~24MB ideal).
__global__ __launch_bounds__(256, 6)
void attn_kernel(const unsigned short* __restrict__ Q,
                 const unsigned short* __restrict__ K,
                 const unsigned short* __restrict__ VT,
                 const float* __restrict__ mbias,
                 unsigned short* __restrict__ Opart,
                 float* __restrict__ Lpart) {
  __shared__ unsigned short sK[64 * 64];  // bf16, row=key, chunk-swizzled
  __shared__ unsigned short sV[64 * 64];  // fp16, row=dim, chunk-swizzled
  __shared__ float sMB[SS / 2];           // mask bias for this split (4KB)
  const int tid = threadIdx.x;
  const int l = tid & 63, w = tid >> 6;
  const int lm = l & 15, qd = l >> 4;
  // XCD swizzle: 2048 blocks = 8 XCDs x 256; logical id contiguous per XCD.
  const int bid = blockIdx.x;
  const int lg = (bid & 7) * 256 + (bid >> 3);
  const int qt = lg & 31;            // q-tile 0..31
  const int h  = (lg >> 5) & 15;     // head
  const int zz = lg >> 9;            // 0..3
  const int b = zz & 1, sp = zz >> 1;
  const int q0 = qt * 64 + w * 16;   // wave: q0 .. q0+15
  const unsigned short* Qh = Q + ((b * NHEAD + h) * SS) * HDIM;
  const unsigned short* Kh = K + ((b * NHEAD + h) * SS) * HDIM;
  const unsigned short* Vh = VT + ((b * NHEAD + h) * HDIM) * SS;
  const float* mb = mbias + b * SS + sp * (SS / 2);
  unsigned short* Op = Opart + sp * (BB * SS * EMBED);
  float* Lp = Lpart + sp * (BB * NHEAD * SS);
  const int kb0 = sp * (SS / 2);

  bf16x8 qf[2];
  qf[0] = *(const bf16x8*)&Qh[(q0 + lm) * HDIM + qd * 8];
  qf[1] = *(const bf16x8*)&Qh[(q0 + lm) * HDIM + 32 + qd * 8];

  auto stageKV = [&](int kb) {
#pragma unroll
    for (int i = 0; i < 2; ++i) {
      const int t = i * 256 + tid;
      const int r = t >> 3;
      const int c = (t & 7) ^ (r & 7);
      g2l16(Kh + (kb + r) * HDIM + c * 8, &sK[(i * 256 + (w << 6)) * 8]);
      g2l16(Vh + r * SS + kb + c * 8, &sV[(i * 256 + (w << 6)) * 8]);
    }
  };

  // one-time mask-bias stage (4KB: 256 lanes x 16B)
  g2l16((const unsigned short*)(mb + tid * 4), (unsigned short*)&sMB[w * 256]);

  f32x4 Od[4];
#pragma unroll
  for (int i = 0; i < 4; ++i) Od[i] = (f32x4){0.f, 0.f, 0.f, 0.f};
  float lsum = 0.f;

  const int NT = (SS / 2) / 64;
  for (int t = 0; t < NT; ++t) {
    // Overwrite of sK/sV is safe: trailing barrier of iter t-1 guarantees
    // all waves finished reading. Leading __syncthreads drains vmcnt(0)
    // (publishes this tile) - implicit in its s_waitcnt.
    stageKV(kb0 + t * 64);
    __syncthreads();

    // Per 32-key group p: QK^T for j=2p,2p+1 -> exp -> pack pf8, then PV.
    // Interleaved per-p to keep pf8 liveness at 8 regs.
#pragma unroll
    for (int p = 0; p < 2; ++p) {
      union PK { hf16x2 h2[4]; f16x8 v; } pk;
#pragma unroll
      for (int jj = 0; jj < 2; ++jj) {
        const int j = p * 2 + jj;
        const int R = j * 16 + lm;
        const bf16x8 k0 = *(const bf16x8*)&sK[(R * 8 + (qd ^ (lm & 7))) * 8];
        const bf16x8 k1 = *(const bf16x8*)&sK[(R * 8 + ((4 + qd) ^ (lm & 7))) * 8];
        const float4 bj = *(const float4*)&sMB[t * 64 + p * 32 + qd * 8 + jj * 4];
        f32x4 t0 = (f32x4){bj.x, bj.y, bj.z, bj.w};
        __builtin_amdgcn_s_setprio(1);
        t0 = __builtin_amdgcn_mfma_f32_16x16x32_bf16(k0, qf[0], t0, 0, 0, 0);
        t0 = __builtin_amdgcn_mfma_f32_16x16x32_bf16(k1, qf[1], t0, 0, 0, 0);
        __builtin_amdgcn_s_setprio(0);
        const float p0 = EXP2(t0[0]);
        const float p1 = EXP2(t0[1]);
        const float p2 = EXP2(t0[2]);
        const float p3 = EXP2(t0[3]);
        lsum += (p0 + p1) + (p2 + p3);
        pk.h2[jj * 2] = __builtin_amdgcn_cvt_pkrtz(p0, p1);
        pk.h2[jj * 2 + 1] = __builtin_amdgcn_cvt_pkrtz(p2, p3);
      }
      const f16x8 pf8 = pk.v;
      // O^T += V-frag x P-frag; K=32 per mfma, b128 conflict-free V reads.
      __builtin_amdgcn_s_setprio(1);
#pragma unroll
      for (int dt = 0; dt < 4; ++dt) {
        const f16x8 vf =
            *(const f16x8*)&sV[(dt * 16 + lm) * 64 + ((p * 4 + qd) ^ (lm & 7)) * 8];
        Od[dt] = __builtin_amdgcn_mfma_f32_16x16x32_f16(vf, pf8, Od[dt], 0, 0, 0);
      }
      __builtin_amdgcn_s_setprio(0);
    }
    __syncthreads();  // all waves done reading sK/sV before next stage
  }

  float ls = lsum;
  ls += __shfl_xor(ls, 16);
  ls += __shfl_xor(ls, 32);
  if (qd == 0) Lp[(b * NHEAD + h) * SS + q0 + lm] = ls;
  // O^T C-layout: lane (qd,lm) holds q=lm, dims dt*16 + qd*4 + r
#pragma unroll
  for (int dt = 0; dt < 4; ++dt) {
    ushort4 u;
    u.x = f2bf(Od[dt][0]); u.y = f2bf(Od[dt][1]);
    u.z = f2bf(Od[dt][2]); u.w = f2bf(Od[dt][3]);
    *(ushort4*)&Op[(b * SS + q0 + lm) * EMBED + h * HDIM + dt * 16 + qd * 4] = u;
  }
}

// ------- combine: Ob = (P0 + P1) / (l0 + l1), bf16 out -------
__global__ __launch_bounds__(256)
void combine_kernel(const unsigned short* __restrict__ Opart,
                    const float* __restrict__ Lpart,
                    unsigned short* __restrict__ Ob) {
  const int i = blockIdx.x * 256 + threadIdx.x;  // per 8 elems
  const int base = i * 8;
  const int token = base >> 10;       // 0..4095
  const int h = (base >> 6) & 15;
  const int b = token >> 11, q = token & 2047;
  const int lidx = (b * NHEAD + h) * SS + q;
  const float ls = Lpart[lidx] + Lpart[BB * NHEAD * SS + lidx];
  const float rinv = 1.f / ls;
  const ushort4* p0 = (const ushort4*)&Opart[base];
  const ushort4* p1 = (const ushort4*)&Opart[BB * SS * EMBED + base];
  ushort4 o[2];
#pragma unroll
  for (int k = 0; k < 2; ++k) {
    const ushort4 a = p0[k], c = p1[k];
    o[k].x = f2bf((bf2f(a.x) + bf2f(c.x)) * rinv);
    o[k].y = f2bf((bf2f(a.y) + bf2f(c.y)) * rinv);
    o[k].z = f2bf((bf2f(a.z) + bf2f(c.z)) * rinv);
    o[k].w = f2bf((bf2f(a.w) + bf2f(c.w)) * rinv);
  }
  *(ushort4*)&Ob[base] = o[0];
  *(ushort4*)&Ob[base + 4] = o[1];
}

extern "C" void kernel_launch(void* const* d_in, const int* in_sizes, int n_in,
                              void* d_out, int out_size, void* d_ws, size_t ws_size,
                              hipStream_t stream) {
  const float* x  = (const float*)d_in[0];
  const int* mask = (const int*)d_in[1];
  const float* Wq = (const float*)d_in[2];
  const float* bq = (const float*)d_in[3];
  const float* Wk = (const float*)d_in[4];
  const float* bk = (const float*)d_in[5];
  const float* Wv = (const float*)d_in[6];
  const float* bv = (const float*)d_in[7];
  const float* Wo = (const float*)d_in[8];
  const float* bo = (const float*)d_in[9];
  float* out = (float*)d_out;

  char* ws = (char*)d_ws;
  const size_t MB = 1024 * 1024;
  // xb [0,8MB) dead after gemm_qkv -> Ob reuses it (combine writes, gemm_out reads)
  unsigned short* xb  = (unsigned short*)(ws);
  unsigned short* Ob  = (unsigned short*)(ws);
  unsigned short* Wqb = (unsigned short*)(ws + 8 * MB);   // 2MB each
  unsigned short* Wkb = Wqb + 1024 * 1024;
  unsigned short* Wvb = Wkb + 1024 * 1024;
  unsigned short* Wob = Wvb + 1024 * 1024;                 // alive till gemm_out
  unsigned short* Qb  = (unsigned short*)(ws + 16 * MB);  // 8MB
  unsigned short* Kb  = (unsigned short*)(ws + 24 * MB);  // 8MB
  unsigned short* VTb = (unsigned short*)(ws + 32 * MB);  // 8MB (fp16)
  unsigned short* Opart = (unsigned short*)(ws + 40 * MB); // 2 x 8MB bf16
  float* mbb   = (float*)(ws + 56 * MB);                   // 16KB
  float* Lpart = (float*)(ws + 56 * MB + 64 * 1024);       // 2 x 256KB

  cvt5_kernel<<<8196, 256, 0, stream>>>(x, Wq, Wk, Wv, Wo, mask,
                                        xb, Wqb, Wkb, Wvb, Wob, mbb);
  gemm_qkv<<<dim3(256, 3), 256, 0, stream>>>(xb, Wqb, Wkb, Wvb, bq, bk, bv,
                                             Qb, Kb, VTb);
  attn_kernel<<<2048, 256, 0, stream>>>(Qb, Kb, VTb, mbb, Opart, Lpart);
  combine_kernel<<<2048, 256, 0, stream>>>(Opart, Lpart, Ob);
  gemm_out<<<512, 256, 0, stream>>>(Wob, Ob, bo, out);
}

// Round 13
// 198.775 us; speedup vs baseline: 1.1801x; 1.0335x over previous
//
#include <hip/hip_runtime.h>

#define EMBED 1024
#define NHEAD 16
#define HDIM  64
#define BB    2
#define SS    2048

typedef __bf16 bf16x8 __attribute__((ext_vector_type(8)));
typedef float  f32x4  __attribute__((ext_vector_type(4)));
typedef _Float16 f16x8 __attribute__((ext_vector_type(8)));
typedef __fp16 hf16x2 __attribute__((ext_vector_type(2)));

#if defined(__has_builtin)
#if __has_builtin(__builtin_amdgcn_exp2f)
#define EXP2(x) __builtin_amdgcn_exp2f(x)
#else
#define EXP2(x) exp2f(x)
#endif
#else
#define EXP2(x) exp2f(x)
#endif

__device__ __forceinline__ unsigned short f2bf(float f) {
  union { float f; unsigned u; } v; v.f = f;
  unsigned r = v.u + 0x7fffu + ((v.u >> 16) & 1u);
  return (unsigned short)(r >> 16);
}

__device__ __forceinline__ float bf2f(unsigned short u) {
  union { unsigned u; float f; } v; v.u = ((unsigned)u) << 16;
  return v.f;
}

__device__ __forceinline__ unsigned short f2h(float f) {
  union { _Float16 h; unsigned short u; } t;
  t.h = (_Float16)f;
  return t.u;
}

__device__ __forceinline__ void g2l16(const unsigned short* g, unsigned short* l) {
  __builtin_amdgcn_global_load_lds(
      (const __attribute__((address_space(1))) unsigned int*)g,
      (__attribute__((address_space(3))) unsigned int*)l, 16, 0, 0);
}

// ------- fused fp32->bf16 convert of x + 4 weights, + maskbias build -------
__global__ __launch_bounds__(256)
void cvt5_kernel(const float* __restrict__ x,  const float* __restrict__ Wq,
                 const float* __restrict__ Wk, const float* __restrict__ Wv,
                 const float* __restrict__ Wo, const int* __restrict__ mask,
                 unsigned short* __restrict__ xb,  unsigned short* __restrict__ Wqb,
                 unsigned short* __restrict__ Wkb, unsigned short* __restrict__ Wvb,
                 unsigned short* __restrict__ Wob, float* __restrict__ mbias) {
  const int i = blockIdx.x * 256 + threadIdx.x;
  if (i < (1 << 21)) {
    const float* src;
    unsigned short* dst;
    int j;
    if (i < (1 << 20)) {
      src = x; dst = xb; j = i;
    } else {
      const int t = i - (1 << 20);
      const int r = t >> 18;
      j = t & ((1 << 18) - 1);
      src = (r == 0) ? Wq : (r == 1) ? Wk : (r == 2) ? Wv : Wo;
      dst = (r == 0) ? Wqb : (r == 1) ? Wkb : (r == 2) ? Wvb : Wob;
    }
    const float4 f = ((const float4*)src)[j];
    ushort4 u;
    u.x = f2bf(f.x); u.y = f2bf(f.y); u.z = f2bf(f.z); u.w = f2bf(f.w);
    ((ushort4*)dst)[j] = u;
  } else {
    const int j = i - (1 << 21);  // 0..1023 int4 groups of mask
    const int4 m = ((const int4*)mask)[j];
    float4 o;
    o.x = m.x ? 0.f : -1e30f; o.y = m.y ? 0.f : -1e30f;
    o.z = m.z ? 0.f : -1e30f; o.w = m.w ? 0.f : -1e30f;
    ((float4*)mbias)[j] = o;
  }
}

// ------- shared 64(m) x 128(n) GEMM core (round-11-verified body) ---------
// C[m][n] = sum_k A[m][k]*Bm[n][k]; LDS 24KB, acc[2][4]=32 VGPR.
template <typename EpiFn>
__device__ __forceinline__
void gemm_core64(const unsigned short* __restrict__ A,
                 const unsigned short* __restrict__ Bm,
                 int m0, int n0, EpiFn epi) {
  __shared__ unsigned short sA[64 * 64];   // 8KB
  __shared__ unsigned short sB[128 * 64];  // 16KB
  const int tid = threadIdx.x;
  const int l  = tid & 63;
  const int w  = tid >> 6;
  const int lm = l & 15;
  const int qd = l >> 4;
  const int wm = w & 1;
  const int wn = w >> 1;

  f32x4 acc[2][4];
#pragma unroll
  for (int i = 0; i < 2; ++i)
#pragma unroll
    for (int j = 0; j < 4; ++j) acc[i][j] = (f32x4){0.f, 0.f, 0.f, 0.f};

  for (int k0 = 0; k0 < EMBED; k0 += 64) {
#pragma unroll
    for (int i = 0; i < 2; ++i) {  // A: 64 rows = 2 rounds
      const int t = i * 256 + tid;
      const int r = t >> 3;
      const int c = (t & 7) ^ (r & 7);
      g2l16(A + (m0 + r) * EMBED + k0 + c * 8, &sA[(i * 256 + (w << 6)) * 8]);
    }
#pragma unroll
    for (int i = 0; i < 4; ++i) {  // B: 128 rows = 4 rounds
      const int t = i * 256 + tid;
      const int r = t >> 3;
      const int c = (t & 7) ^ (r & 7);
      g2l16(Bm + (n0 + r) * EMBED + k0 + c * 8, &sB[(i * 256 + (w << 6)) * 8]);
    }
    __syncthreads();
#pragma unroll
    for (int kk = 0; kk < 2; ++kk) {
      bf16x8 af[2], bfr[4];
#pragma unroll
      for (int mi = 0; mi < 2; ++mi) {
        const int R = wm * 32 + mi * 16 + lm;
        const int ch = R * 8 + (((kk << 2) + qd) ^ (R & 7));
        af[mi] = *(const bf16x8*)&sA[ch * 8];
      }
#pragma unroll
      for (int ni = 0; ni < 4; ++ni) {
        const int R = wn * 64 + ni * 16 + lm;
        const int ch = R * 8 + (((kk << 2) + qd) ^ (R & 7));
        bfr[ni] = *(const bf16x8*)&sB[ch * 8];
      }
#pragma unroll
      for (int mi = 0; mi < 2; ++mi)
#pragma unroll
        for (int ni = 0; ni < 4; ++ni)
          acc[mi][ni] = __builtin_amdgcn_mfma_f32_16x16x32_bf16(
              af[mi], bfr[ni], acc[mi][ni], 0, 0, 0);
    }
    __syncthreads();
  }

#pragma unroll
  for (int mi = 0; mi < 2; ++mi)
#pragma unroll
    for (int ni = 0; ni < 4; ++ni) {
      const int mb = m0 + wm * 32 + mi * 16 + qd * 4;  // rows mb..mb+3
      const int n  = n0 + wn * 64 + ni * 16 + lm;
      epi(acc[mi][ni], mb, n);
    }
}

// ------- fused Q/K/V projection: 64x128 tiles, 512 blocks/z, XCD swizzle ---
// z=0: Q = Wq·x^T ->(b,h,s,d) bf16, pre-scaled by (1/8)*log2(e)
// z=1: K = Wk·x^T ->(b,h,s,d) bf16, tokens PERMUTED within 32-groups (attn
//      S^T lane layout PV-contiguity): token w -> row ((w>>2)&1)*16 +
//      ((w>>3)&3)*4 + (w&3) of its 32-block.
// z=2: V = x·Wv^T ->(b,h,d,s) fp16 (transposed, for PV MFMA)
// 64-m tiles: grid 512x3 = 1536 = 6 blocks/CU (was 768 = 3/CU at 128^2) --
// round-9/11 lesson: these GEMMs are latency-exposed; more blocks/CU is the
// lever. XCD swizzle: lg contiguous per XCD (512%8==0, bijective);
// m-fastest order -> each XCD works 4 B-panels (z<2) or 1 weight panel
// (z=2): ~3MB < 4MB per-XCD L2.
__global__ __launch_bounds__(256)
void gemm_qkv(const unsigned short* __restrict__ xb,
              const unsigned short* __restrict__ Wqb,
              const unsigned short* __restrict__ Wkb,
              const unsigned short* __restrict__ Wvb,
              const float* __restrict__ bq, const float* __restrict__ bk,
              const float* __restrict__ bv,
              unsigned short* __restrict__ Qb, unsigned short* __restrict__ Kb,
              unsigned short* __restrict__ VTb) {
  const int z = blockIdx.y;
  const int bid = blockIdx.x;                   // 0..511
  const int lg = (bid & 7) * 64 + (bid >> 3);   // XCD-contiguous logical id
  if (z < 2) {
    const unsigned short* A = z ? Wkb : Wqb;
    const float* bias = z ? bk : bq;
    unsigned short* O = z ? Kb : Qb;
    const float scale = z ? 1.0f : 0.125f * 1.4426950408889634f;
    const int m0 = (lg & 15) * 64;    // feature tile (16)
    const int n0 = (lg >> 4) * 128;   // token tile (32)
    gemm_core64(A, xb, m0, n0, [&](const f32x4& v, int mb, int n) {
      const float4 bvv = *(const float4*)&bias[mb];
      const int h = mb >> 6, d0 = mb & 63;
      const int b = n >> 11, s = n & 2047;
      int sw = s;
      if (z == 1)
        sw = (s & ~31) | (((s >> 2) & 1) << 4) | (((s >> 3) & 3) << 2) | (s & 3);
      ushort4 u;
      u.x = f2bf((v.x + bvv.x) * scale); u.y = f2bf((v.y + bvv.y) * scale);
      u.z = f2bf((v.z + bvv.z) * scale); u.w = f2bf((v.w + bvv.w) * scale);
      *(ushort4*)&O[(((b * NHEAD + h) * SS) + sw) * HDIM + d0] = u;
    });
  } else {
    const int m0 = (lg & 63) * 64;    // token tile (64)
    const int n0 = (lg >> 6) * 128;   // feature tile (8)
    gemm_core64(xb, Wvb, m0, n0, [&](const f32x4& v, int mb, int n) {
      const float bvv = bv[n];
      const int b = mb >> 11, s = mb & 2047;
      const int h = n >> 6, d = n & 63;
      ushort4 u;
      u.x = f2h(v.x + bvv); u.y = f2h(v.y + bvv);
      u.z = f2h(v.z + bvv); u.w = f2h(v.w + bvv);
      *(ushort4*)&VTb[(((b * NHEAD + h) * HDIM) + d) * SS + s] = u;
    });
  }
}

// ------- output projection: 64x128 tile + XCD swizzle --------------------
__global__ __launch_bounds__(256)
void gemm_out(const unsigned short* __restrict__ Wob,
              const unsigned short* __restrict__ Ob,
              const float* __restrict__ bo, float* __restrict__ out) {
  const int bid = blockIdx.x;                   // 0..511
  const int lg = (bid & 7) * 64 + (bid >> 3);   // XCD-contiguous logical id
  const int m0 = (lg & 15) * 64;    // feature tile (16)
  const int n0 = (lg >> 4) * 128;   // token tile (32)
  gemm_core64(Wob, Ob, m0, n0, [&](const f32x4& v, int mb, int n) {
    const float4 bvv = *(const float4*)&bo[mb];
    float4 o;
    o.x = v.x + bvv.x; o.y = v.y + bvv.y; o.z = v.z + bvv.z; o.w = v.w + bvv.w;
    *(float4*)&out[n * EMBED + mb] = o;
  });
}

// ------- flash attention, key-split x2, 16 q per wave, 8 blocks/CU ---------
// (round-6 compute + round-12 T1 XCD swizzle: FETCH 71.8->16.5MB verified)
__global__ __launch_bounds__(256, 6)
void attn_kernel(const unsigned short* __restrict__ Q,
                 const unsigned short* __restrict__ K,
                 const unsigned short* __restrict__ VT,
                 const float* __restrict__ mbias,
                 unsigned short* __restrict__ Opart,
                 float* __restrict__ Lpart) {
  __shared__ unsigned short sK[64 * 64];  // bf16, row=key, chunk-swizzled
  __shared__ unsigned short sV[64 * 64];  // fp16, row=dim, chunk-swizzled
  __shared__ float sMB[SS / 2];           // mask bias for this split (4KB)
  const int tid = threadIdx.x;
  const int l = tid & 63, w = tid >> 6;
  const int lm = l & 15, qd = l >> 4;
  // XCD swizzle: 2048 blocks = 8 XCDs x 256; logical id contiguous per XCD.
  const int bid = blockIdx.x;
  const int lg = (bid & 7) * 256 + (bid >> 3);
  const int qt = lg & 31;            // q-tile 0..31
  const int h  = (lg >> 5) & 15;     // head
  const int zz = lg >> 9;            // 0..3
  const int b = zz & 1, sp = zz >> 1;
  const int q0 = qt * 64 + w * 16;   // wave: q0 .. q0+15
  const unsigned short* Qh = Q + ((b * NHEAD + h) * SS) * HDIM;
  const unsigned short* Kh = K + ((b * NHEAD + h) * SS) * HDIM;
  const unsigned short* Vh = VT + ((b * NHEAD + h) * HDIM) * SS;
  const float* mb = mbias + b * SS + sp * (SS / 2);
  unsigned short* Op = Opart + sp * (BB * SS * EMBED);
  float* Lp = Lpart + sp * (BB * NHEAD * SS);
  const int kb0 = sp * (SS / 2);

  bf16x8 qf[2];
  qf[0] = *(const bf16x8*)&Qh[(q0 + lm) * HDIM + qd * 8];
  qf[1] = *(const bf16x8*)&Qh[(q0 + lm) * HDIM + 32 + qd * 8];

  auto stageKV = [&](int kb) {
#pragma unroll
    for (int i = 0; i < 2; ++i) {
      const int t = i * 256 + tid;
      const int r = t >> 3;
      const int c = (t & 7) ^ (r & 7);
      g2l16(Kh + (kb + r) * HDIM + c * 8, &sK[(i * 256 + (w << 6)) * 8]);
      g2l16(Vh + r * SS + kb + c * 8, &sV[(i * 256 + (w << 6)) * 8]);
    }
  };

  // one-time mask-bias stage (4KB: 256 lanes x 16B)
  g2l16((const unsigned short*)(mb + tid * 4), (unsigned short*)&sMB[w * 256]);

  f32x4 Od[4];
#pragma unroll
  for (int i = 0; i < 4; ++i) Od[i] = (f32x4){0.f, 0.f, 0.f, 0.f};
  float lsum = 0.f;

  const int NT = (SS / 2) / 64;
  for (int t = 0; t < NT; ++t) {
    // Overwrite of sK/sV is safe: trailing barrier of iter t-1 guarantees
    // all waves finished reading. Leading __syncthreads drains vmcnt(0)
    // (publishes this tile) - implicit in its s_waitcnt.
    stageKV(kb0 + t * 64);
    __syncthreads();

    // Per 32-key group p: QK^T for j=2p,2p+1 -> exp -> pack pf8, then PV.
    // Interleaved per-p to keep pf8 liveness at 8 regs.
#pragma unroll
    for (int p = 0; p < 2; ++p) {
      union PK { hf16x2 h2[4]; f16x8 v; } pk;
#pragma unroll
      for (int jj = 0; jj < 2; ++jj) {
        const int j = p * 2 + jj;
        const int R = j * 16 + lm;
        const bf16x8 k0 = *(const bf16x8*)&sK[(R * 8 + (qd ^ (lm & 7))) * 8];
        const bf16x8 k1 = *(const bf16x8*)&sK[(R * 8 + ((4 + qd) ^ (lm & 7))) * 8];
        const float4 bj = *(const float4*)&sMB[t * 64 + p * 32 + qd * 8 + jj * 4];
        f32x4 t0 = (f32x4){bj.x, bj.y, bj.z, bj.w};
        __builtin_amdgcn_s_setprio(1);
        t0 = __builtin_amdgcn_mfma_f32_16x16x32_bf16(k0, qf[0], t0, 0, 0, 0);
        t0 = __builtin_amdgcn_mfma_f32_16x16x32_bf16(k1, qf[1], t0, 0, 0, 0);
        __builtin_amdgcn_s_setprio(0);
        const float p0 = EXP2(t0[0]);
        const float p1 = EXP2(t0[1]);
        const float p2 = EXP2(t0[2]);
        const float p3 = EXP2(t0[3]);
        lsum += (p0 + p1) + (p2 + p3);
        pk.h2[jj * 2] = __builtin_amdgcn_cvt_pkrtz(p0, p1);
        pk.h2[jj * 2 + 1] = __builtin_amdgcn_cvt_pkrtz(p2, p3);
      }
      const f16x8 pf8 = pk.v;
      // O^T += V-frag x P-frag; K=32 per mfma, b128 conflict-free V reads.
      __builtin_amdgcn_s_setprio(1);
#pragma unroll
      for (int dt = 0; dt < 4; ++dt) {
        const f16x8 vf =
            *(const f16x8*)&sV[(dt * 16 + lm) * 64 + ((p * 4 + qd) ^ (lm & 7)) * 8];
        Od[dt] = __builtin_amdgcn_mfma_f32_16x16x32_f16(vf, pf8, Od[dt], 0, 0, 0);
      }
      __builtin_amdgcn_s_setprio(0);
    }
    __syncthreads();  // all waves done reading sK/sV before next stage
  }

  float ls = lsum;
  ls += __shfl_xor(ls, 16);
  ls += __shfl_xor(ls, 32);
  if (qd == 0) Lp[(b * NHEAD + h) * SS + q0 + lm] = ls;
  // O^T C-layout: lane (qd,lm) holds q=lm, dims dt*16 + qd*4 + r
#pragma unroll
  for (int dt = 0; dt < 4; ++dt) {
    ushort4 u;
    u.x = f2bf(Od[dt][0]); u.y = f2bf(Od[dt][1]);
    u.z = f2bf(Od[dt][2]); u.w = f2bf(Od[dt][3]);
    *(ushort4*)&Op[(b * SS + q0 + lm) * EMBED + h * HDIM + dt * 16 + qd * 4] = u;
  }
}

// ------- combine: Ob = (P0 + P1) / (l0 + l1), bf16 out -------
__global__ __launch_bounds__(256)
void combine_kernel(const unsigned short* __restrict__ Opart,
                    const float* __restrict__ Lpart,
                    unsigned short* __restrict__ Ob) {
  const int i = blockIdx.x * 256 + threadIdx.x;  // per 8 elems
  const int base = i * 8;
  const int token = base >> 10;       // 0..4095
  const int h = (base >> 6) & 15;
  const int b = token >> 11, q = token & 2047;
  const int lidx = (b * NHEAD + h) * SS + q;
  const float ls = Lpart[lidx] + Lpart[BB * NHEAD * SS + lidx];
  const float rinv = 1.f / ls;
  const ushort4* p0 = (const ushort4*)&Opart[base];
  const ushort4* p1 = (const ushort4*)&Opart[BB * SS * EMBED + base];
  ushort4 o[2];
#pragma unroll
  for (int k = 0; k < 2; ++k) {
    const ushort4 a = p0[k], c = p1[k];
    o[k].x = f2bf((bf2f(a.x) + bf2f(c.x)) * rinv);
    o[k].y = f2bf((bf2f(a.y) + bf2f(c.y)) * rinv);
    o[k].z = f2bf((bf2f(a.z) + bf2f(c.z)) * rinv);
    o[k].w = f2bf((bf2f(a.w) + bf2f(c.w)) * rinv);
  }
  *(ushort4*)&Ob[base] = o[0];
  *(ushort4*)&Ob[base + 4] = o[1];
}

extern "C" void kernel_launch(void* const* d_in, const int* in_sizes, int n_in,
                              void* d_out, int out_size, void* d_ws, size_t ws_size,
                              hipStream_t stream) {
  const float* x  = (const float*)d_in[0];
  const int* mask = (const int*)d_in[1];
  const float* Wq = (const float*)d_in[2];
  const float* bq = (const float*)d_in[3];
  const float* Wk = (const float*)d_in[4];
  const float* bk = (const float*)d_in[5];
  const float* Wv = (const float*)d_in[6];
  const float* bv = (const float*)d_in[7];
  const float* Wo = (const float*)d_in[8];
  const float* bo = (const float*)d_in[9];
  float* out = (float*)d_out;

  char* ws = (char*)d_ws;
  const size_t MB = 1024 * 1024;
  // xb [0,8MB) dead after gemm_qkv -> Ob reuses it (combine writes, gemm_out reads)
  unsigned short* xb  = (unsigned short*)(ws);
  unsigned short* Ob  = (unsigned short*)(ws);
  unsigned short* Wqb = (unsigned short*)(ws + 8 * MB);   // 2MB each
  unsigned short* Wkb = Wqb + 1024 * 1024;
  unsigned short* Wvb = Wkb + 1024 * 1024;
  unsigned short* Wob = Wvb + 1024 * 1024;                 // alive till gemm_out
  unsigned short* Qb  = (unsigned short*)(ws + 16 * MB);  // 8MB
  unsigned short* Kb  = (unsigned short*)(ws + 24 * MB);  // 8MB
  unsigned short* VTb = (unsigned short*)(ws + 32 * MB);  // 8MB (fp16)
  unsigned short* Opart = (unsigned short*)(ws + 40 * MB); // 2 x 8MB bf16
  float* mbb   = (float*)(ws + 56 * MB);                   // 16KB
  float* Lpart = (float*)(ws + 56 * MB + 64 * 1024);       // 2 x 256KB

  cvt5_kernel<<<8196, 256, 0, stream>>>(x, Wq, Wk, Wv, Wo, mask,
                                        xb, Wqb, Wkb, Wvb, Wob, mbb);
  gemm_qkv<<<dim3(512, 3), 256, 0, stream>>>(xb, Wqb, Wkb, Wvb, bq, bk, bv,
                                             Qb, Kb, VTb);
  attn_kernel<<<2048, 256, 0, stream>>>(Qb, Kb, VTb, mbb, Opart, Lpart);
  combine_kernel<<<2048, 256, 0, stream>>>(Opart, Lpart, Ob);
  gemm_out<<<512, 256, 0, stream>>>(Wob, Ob, bo, out);
}